// Round 2
// baseline (3793.534 us; speedup 1.0000x reference)
//
#include <hip/hip_runtime.h>
#include <hip/hip_bf16.h>
#include <math.h>

#define T_ 1024
#define H_ 2048
#define NH_ 16
#define NKV_ 4
#define HD_ 128
#define E_ 32
#define TOPK_ 4
#define I_ 1024
#define QKVN_ 3072
#define EPS_ 1e-6f
#define THETA_ 600000.0f
#define SCALE_ 0.08838834764831845f

typedef unsigned short u16;
typedef u16 u16x4 __attribute__((ext_vector_type(4)));
typedef u16 u16x8 __attribute__((ext_vector_type(8)));
typedef __bf16 bf16x8 __attribute__((ext_vector_type(8)));
typedef float f32x4 __attribute__((ext_vector_type(4)));

__device__ __forceinline__ u16 f2b(float f) {
  unsigned u = __builtin_bit_cast(unsigned, f);
  u += 0x7FFFu + ((u >> 16) & 1u);
  return (u16)(u >> 16);
}
__device__ __forceinline__ float b2f(u16 x) {
  unsigned u = ((unsigned)x) << 16;
  return __builtin_bit_cast(float, u);
}

// ---------------------------------------------------------------------------
// Generic 128x128 (BK=64) bf16 MFMA GEMM. 256 threads = 4 waves, each wave
// owns a 64x64 sub-tile = 4x4 fragments of 16x16x32.
// A: bf16 bits [M][lda] (optionally gathered rows via slots[])
// B: BTL ? B[n][k] (ldb=K-stride) : B[k][n] (ldb=N-stride); TB = float|u16
// EPI: 0 bf16 store (grouped: at global slot row) | 1 bf16 store *alpha |
//      2 f32 store res1+acc | 3 atomicAdd slotw*acc into Cf[token] |
//      4 f32 store res1+res2+acc
// ---------------------------------------------------------------------------
template<typename TB, bool BTL, bool GROUPED, bool GATHER, int EPI>
__global__ __launch_bounds__(256) void gemm_k(
    const u16* __restrict__ A, const TB* __restrict__ B,
    u16* __restrict__ Cb, float* __restrict__ Cf,
    const float* __restrict__ res1, const float* __restrict__ res2,
    int M, int N, int K, int lda, int ldb, int ldc,
    float alpha, int causal, int mbmax,
    const int* __restrict__ eoff, const int* __restrict__ slots,
    const float* __restrict__ slotw,
    long long sAz, long long sBz, long long sCz, int bdivz)
{
  __shared__ u16 As[128 * 64];
  __shared__ u16 Bs[128 * 64];

  int m0, n0, Mloc, goff = 0;
  const u16* Ae = A;
  const TB* Be = B;
  if (GROUPED) {
    int e = blockIdx.x / mbmax;
    int mb = blockIdx.x - e * mbmax;
    goff = eoff[e];
    Mloc = eoff[e + 1] - goff;
    m0 = mb * 128;
    if (m0 >= Mloc) return;
    n0 = blockIdx.y * 128;
    Be = B + (long long)e * sBz;
    if (!GATHER) Ae = A + (long long)goff * lda;
  } else {
    m0 = blockIdx.x * 128;
    n0 = blockIdx.y * 128;
    Mloc = M;
    long long z = blockIdx.z;
    Ae = A + z * sAz;
    Be = B + (long long)(z / bdivz) * sBz;
    if (Cb) Cb += z * sCz;
    if (causal && n0 > m0 + 127) return;
  }

  const int tid = threadIdx.x;
  const int lane = tid & 63;
  const int wv = tid >> 6;
  const int wr = wv >> 1, wc = wv & 1;

  f32x4 acc[4][4];
  #pragma unroll
  for (int i = 0; i < 4; ++i)
    #pragma unroll
    for (int j = 0; j < 4; ++j)
      acc[i][j] = f32x4{0.f, 0.f, 0.f, 0.f};

  for (int k0 = 0; k0 < K; k0 += 64) {
    // ---- stage A (bf16 bits) ----
    #pragma unroll
    for (int it = 0; it < 4; ++it) {
      int idx = it * 2048 + tid * 8;
      int r = idx >> 6, kk = idx & 63;
      u16x8 v = u16x8{0, 0, 0, 0, 0, 0, 0, 0};
      if (m0 + r < Mloc) {
        long long row = GATHER ? (long long)slots[goff + m0 + r] : (long long)(m0 + r);
        v = *(const u16x8*)(Ae + row * (long long)lda + k0 + kk);
      }
      *(u16x8*)(As + r * 64 + kk) = v;
    }
    // ---- stage B ----
    if constexpr (BTL) {
      if constexpr (sizeof(TB) == 4) {
        const float* Bf = (const float*)Be;
        #pragma unroll
        for (int it = 0; it < 8; ++it) {
          int idx = it * 1024 + tid * 4;
          int n = idx >> 6, kk = idx & 63;
          float4 f = *(const float4*)(Bf + (long long)(n0 + n) * ldb + k0 + kk);
          u16x4 o = u16x4{f2b(f.x), f2b(f.y), f2b(f.z), f2b(f.w)};
          *(u16x4*)(Bs + n * 64 + kk) = o;
        }
      } else {
        const u16* Bb = (const u16*)Be;
        #pragma unroll
        for (int it = 0; it < 4; ++it) {
          int idx = it * 2048 + tid * 8;
          int n = idx >> 6, kk = idx & 63;
          u16x8 v = *(const u16x8*)(Bb + (long long)(n0 + n) * ldb + k0 + kk);
          *(u16x8*)(Bs + n * 64 + kk) = v;
        }
      }
    } else {
      if constexpr (sizeof(TB) == 4) {
        const float* Bf = (const float*)Be;
        #pragma unroll
        for (int it = 0; it < 8; ++it) {
          int idx = it * 1024 + tid * 4;
          int kk = idx >> 7, n = idx & 127;
          float4 f = *(const float4*)(Bf + (long long)(k0 + kk) * ldb + n0 + n);
          Bs[(n + 0) * 64 + kk] = f2b(f.x);
          Bs[(n + 1) * 64 + kk] = f2b(f.y);
          Bs[(n + 2) * 64 + kk] = f2b(f.z);
          Bs[(n + 3) * 64 + kk] = f2b(f.w);
        }
      } else {
        const u16* Bb = (const u16*)Be;
        #pragma unroll
        for (int it = 0; it < 4; ++it) {
          int idx = it * 2048 + tid * 8;
          int kk = idx >> 7, n = idx & 127;
          u16x8 v = *(const u16x8*)(Bb + (long long)(k0 + kk) * ldb + n0 + n);
          #pragma unroll
          for (int q = 0; q < 8; ++q) Bs[(n + q) * 64 + kk] = v[q];
        }
      }
    }
    __syncthreads();
    // ---- MFMA ----
    #pragma unroll
    for (int kk = 0; kk < 64; kk += 32) {
      int kb = kk + ((lane >> 4) << 3);
      int ar = (wr << 6) + (lane & 15);
      int bc = (wc << 6) + (lane & 15);
      bf16x8 af[4], bfr[4];
      #pragma unroll
      for (int m = 0; m < 4; ++m)
        af[m] = __builtin_bit_cast(bf16x8, *(const u16x8*)(As + (ar + m * 16) * 64 + kb));
      #pragma unroll
      for (int n = 0; n < 4; ++n)
        bfr[n] = __builtin_bit_cast(bf16x8, *(const u16x8*)(Bs + (bc + n * 16) * 64 + kb));
      #pragma unroll
      for (int m = 0; m < 4; ++m)
        #pragma unroll
        for (int n = 0; n < 4; ++n)
          acc[m][n] = __builtin_amdgcn_mfma_f32_16x16x32_bf16(af[m], bfr[n], acc[m][n], 0, 0, 0);
    }
    __syncthreads();
  }
  // ---- epilogue: C/D layout col=lane&15, row=(lane>>4)*4+j ----
  const int cr = lane & 15, rq = lane >> 4;
  #pragma unroll
  for (int m = 0; m < 4; ++m) {
    #pragma unroll
    for (int j = 0; j < 4; ++j) {
      int row = m0 + (wr << 6) + m * 16 + rq * 4 + j;
      if (row >= Mloc) continue;
      #pragma unroll
      for (int n = 0; n < 4; ++n) {
        int col = n0 + (wc << 6) + n * 16 + cr;
        float v = acc[m][n][j];
        long long o = (long long)(goff + row) * ldc + col;  // goff=0 if !GROUPED
        if constexpr (EPI == 0) {
          Cb[o] = f2b(v);
        } else if constexpr (EPI == 1) {
          Cb[o] = f2b(v * alpha);
        } else if constexpr (EPI == 2) {
          Cf[o] = res1[o] + v;
        } else if constexpr (EPI == 3) {
          int tok = slots[goff + row];
          float wgt = slotw[goff + row];
          atomicAdd(&Cf[(long long)tok * ldc + col], wgt * v);
        } else {
          Cf[o] = res1[o] + res2[o] + v;
        }
      }
    }
  }
}

// ---------------------------------------------------------------------------
__global__ __launch_bounds__(256) void rmsnorm_k(const float* __restrict__ x,
                                                 const float* __restrict__ w,
                                                 u16* __restrict__ outb,
                                                 float* __restrict__ outf) {
  int t = blockIdx.x;
  int tid = threadIdx.x;
  const float* xr = x + (long long)t * H_;
  float4 a = *(const float4*)(xr + tid * 8);
  float4 b = *(const float4*)(xr + tid * 8 + 4);
  float ss = a.x * a.x + a.y * a.y + a.z * a.z + a.w * a.w +
             b.x * b.x + b.y * b.y + b.z * b.z + b.w * b.w;
  #pragma unroll
  for (int o = 32; o; o >>= 1) ss += __shfl_down(ss, o);
  __shared__ float red[4];
  if ((tid & 63) == 0) red[tid >> 6] = ss;
  __syncthreads();
  float sc = rsqrtf((red[0] + red[1] + red[2] + red[3]) * (1.0f / H_) + EPS_);
  float vo[8] = {a.x, a.y, a.z, a.w, b.x, b.y, b.z, b.w};
  const float* wr = w + tid * 8;
  u16x8 ob;
  #pragma unroll
  for (int q = 0; q < 8; ++q) {
    float val = vo[q] * sc * wr[q];
    ob[q] = f2b(val);
    if (outf) outf[(long long)t * H_ + tid * 8 + q] = val;
  }
  *(u16x8*)(outb + (long long)t * H_ + tid * 8) = ob;
}

// qkv [T][3072] bf16 -> q_r [NH][T][HD], k_r [NKV][T][HD] (roped), v_r [NKV][T][HD]
__global__ __launch_bounds__(256) void rope_k(const u16* __restrict__ qkv,
                                              const int* __restrict__ pos,
                                              u16* __restrict__ q_r,
                                              u16* __restrict__ k_r,
                                              u16* __restrict__ v_r) {
  int t = blockIdx.x;
  int tid = threadIdx.x;
  float p = (float)pos[t];
  const u16* row = qkv + (long long)t * QKVN_;
  const float cfac = logf(THETA_) * (1.0f / 64.0f);
  #pragma unroll
  for (int it = 0; it < 4; ++it) {
    int item = it * 256 + tid;
    int h = item >> 6, d = item & 63;
    float inv = expf(-cfac * (float)d);
    float ang = p * inv;
    float c = cosf(ang), s = sinf(ang);
    float x1v = b2f(row[h * 128 + d]);
    float x2v = b2f(row[h * 128 + 64 + d]);
    u16* dst = q_r + ((long long)h * T_ + t) * HD_;
    dst[d] = f2b(x1v * c - x2v * s);
    dst[d + 64] = f2b(x1v * s + x2v * c);
  }
  {
    int item = tid;
    int kv = item >> 6, d = item & 63;
    float inv = expf(-cfac * (float)d);
    float ang = p * inv;
    float c = cosf(ang), s = sinf(ang);
    float x1v = b2f(row[NH_ * HD_ + kv * 128 + d]);
    float x2v = b2f(row[NH_ * HD_ + kv * 128 + 64 + d]);
    u16* dst = k_r + ((long long)kv * T_ + t) * HD_;
    dst[d] = f2b(x1v * c - x2v * s);
    dst[d + 64] = f2b(x1v * s + x2v * c);
  }
  #pragma unroll
  for (int it = 0; it < 2; ++it) {
    int item = it * 256 + tid;
    int kv = item >> 7, d = item & 127;
    v_r[((long long)kv * T_ + t) * HD_ + d] = row[(NH_ + NKV_) * HD_ + kv * 128 + d];
  }
}

// in-place masked softmax of one (head, row) per 64-thread block
__global__ __launch_bounds__(64) void softmax_k(u16* __restrict__ P) {
  int r = blockIdx.x;
  int h = r >> 10, i = r & 1023;
  u16* row = P + ((long long)h * T_ + i) * T_;
  int lane = threadIdx.x;
  int n = i + 1;
  float vals[16];
  float mx = -1e30f;
  #pragma unroll
  for (int it = 0; it < 16; ++it) {
    int j = it * 64 + lane;
    float s = (j < n) ? b2f(row[j]) : -1e30f;
    vals[it] = s;
    mx = fmaxf(mx, s);
  }
  #pragma unroll
  for (int o = 32; o; o >>= 1) mx = fmaxf(mx, __shfl_xor(mx, o));
  float sum = 0.f;
  #pragma unroll
  for (int it = 0; it < 16; ++it) {
    int j = it * 64 + lane;
    float e = (j < n) ? __expf(vals[it] - mx) : 0.f;
    vals[it] = e;
    sum += e;
  }
  #pragma unroll
  for (int o = 32; o; o >>= 1) sum += __shfl_xor(sum, o);
  float inv = 1.f / sum;
  #pragma unroll
  for (int it = 0; it < 16; ++it) {
    int j = it * 64 + lane;
    row[j] = f2b(vals[it] * inv);
  }
}

// one (t,e) dot product per 64-thread block
__global__ __launch_bounds__(64) void router_k(const float* __restrict__ h2,
                                               const float* __restrict__ wr,
                                               float* __restrict__ logits) {
  int b = blockIdx.x;
  int t = b >> 5, e = b & 31;
  const float* xr = h2 + (long long)t * H_;
  const float* wv = wr + (long long)e * H_;
  int lane = threadIdx.x;
  float s = 0.f;
  #pragma unroll
  for (int it = 0; it < 8; ++it) {
    int h = it * 256 + lane * 4;
    float4 a = *(const float4*)(xr + h);
    float4 w4 = *(const float4*)(wv + h);
    s += a.x * w4.x + a.y * w4.y + a.z * w4.z + a.w * w4.w;
  }
  #pragma unroll
  for (int o = 32; o; o >>= 1) s += __shfl_xor(s, o);
  if (lane == 0) logits[b] = s;
}

__global__ __launch_bounds__(256) void topk_k(const float* __restrict__ logits,
                                              int* __restrict__ topi,
                                              float* __restrict__ topw) {
  int t = blockIdx.x * 256 + threadIdx.x;
  if (t >= T_) return;
  float l[E_];
  #pragma unroll
  for (int e = 0; e < E_; ++e) l[e] = logits[t * E_ + e];
  int sel[TOPK_];
  float sv[TOPK_];
  unsigned used = 0;
  for (int j = 0; j < TOPK_; ++j) {
    float best = -1e30f;
    int bi = 0;
    for (int e = 0; e < E_; ++e) {
      if (used & (1u << e)) continue;
      if (l[e] > best) { best = l[e]; bi = e; }
    }
    used |= 1u << bi;
    sel[j] = bi;
    sv[j] = best;
  }
  float mx = sv[0];
  float s = 0.f;
  #pragma unroll
  for (int j = 0; j < TOPK_; ++j) { sv[j] = __expf(sv[j] - mx); s += sv[j]; }
  float inv = 1.f / s;
  #pragma unroll
  for (int j = 0; j < TOPK_; ++j) {
    topi[t * TOPK_ + j] = sel[j];
    topw[t * TOPK_ + j] = sv[j] * inv;
  }
}

__global__ __launch_bounds__(256) void hist_k(const int* __restrict__ topi, int* __restrict__ cnt) {
  int idx = blockIdx.x * 256 + threadIdx.x;
  if (idx < T_ * TOPK_) atomicAdd(&cnt[topi[idx]], 1);
}

__global__ __launch_bounds__(64) void scan_k(const int* __restrict__ cnt,
                                             int* __restrict__ eoff,
                                             int* __restrict__ cursor) {
  if (threadIdx.x == 0) {
    int s = 0;
    for (int e = 0; e < E_; ++e) { eoff[e] = s; cursor[e] = s; s += cnt[e]; }
    eoff[E_] = s;
  }
}

__global__ __launch_bounds__(256) void scatter_k(const int* __restrict__ topi,
                                                 const float* __restrict__ topw,
                                                 int* __restrict__ cursor,
                                                 int* __restrict__ slots,
                                                 float* __restrict__ slotw) {
  int idx = blockIdx.x * 256 + threadIdx.x;
  if (idx >= T_ * TOPK_) return;
  int e = topi[idx];
  int pos = atomicAdd(&cursor[e], 1);
  slots[pos] = idx >> 2;
  slotw[pos] = topw[idx];
}

__global__ __launch_bounds__(256) void silumul_k(const u16* __restrict__ g,
                                                 const u16* __restrict__ u,
                                                 u16* __restrict__ a) {
  long long idx = ((long long)blockIdx.x * 256 + threadIdx.x) * 8;
  u16x8 gv = *(const u16x8*)(g + idx);
  u16x8 uv = *(const u16x8*)(u + idx);
  u16x8 o;
  #pragma unroll
  for (int q = 0; q < 8; ++q) {
    float x = b2f(gv[q]);
    float y = b2f(uv[q]);
    float sl = x / (1.f + __expf(-x));
    o[q] = f2b(sl * y);
  }
  *(u16x8*)(a + idx) = o;
}

__global__ __launch_bounds__(256) void sharedact_k(const u16* __restrict__ gu,
                                                   u16* __restrict__ act) {
  long long idx = ((long long)blockIdx.x * 256 + threadIdx.x) * 8;
  long long t = idx >> 10;
  int i = (int)(idx & 1023);
  const u16* row = gu + t * (2 * I_);
  u16x8 g = *(const u16x8*)(row + i);
  u16x8 u = *(const u16x8*)(row + I_ + i);
  u16x8 o;
  #pragma unroll
  for (int q = 0; q < 8; ++q) {
    float x = b2f(g[q]);
    float y = b2f(u[q]);
    float sl = x / (1.f + __expf(-x));
    o[q] = f2b(sl * y);
  }
  *(u16x8*)(act + t * I_ + i) = o;
}

// ---------------------------------------------------------------------------
extern "C" void kernel_launch(void* const* d_in, const int* in_sizes, int n_in,
                              void* d_out, int out_size, void* d_ws, size_t ws_size,
                              hipStream_t stream) {
  const float* x        = (const float*)d_in[0];
  const int* positions  = (const int*)d_in[1];
  const float* w_rms1   = (const float*)d_in[2];
  const float* w_rms2   = (const float*)d_in[3];
  const float* w_qkv    = (const float*)d_in[4];
  const float* w_o      = (const float*)d_in[5];
  const float* w_router = (const float*)d_in[6];
  const float* w1       = (const float*)d_in[7];
  const float* w3       = (const float*)d_in[8];
  const float* w2       = (const float*)d_in[9];
  const float* ws_gu    = (const float*)d_in[10];
  const float* ws_dn    = (const float*)d_in[11];
  float* out = (float*)d_out;   // reference output dtype is float32

  char* ws = (char*)d_ws;
  size_t off = 0;
  auto alloc = [&](size_t bytes) {
    size_t o = off;
    off = (off + bytes + 255) & ~(size_t)255;
    return (void*)(ws + o);
  };
  u16*  h1b     = (u16*)alloc((size_t)T_ * H_ * 2);
  u16*  qkvb    = (u16*)alloc((size_t)T_ * QKVN_ * 2);
  u16*  q_r     = (u16*)alloc((size_t)NH_ * T_ * HD_ * 2);
  u16*  k_r     = (u16*)alloc((size_t)NKV_ * T_ * HD_ * 2);
  u16*  v_r     = (u16*)alloc((size_t)NKV_ * T_ * HD_ * 2);
  u16*  scoresP = (u16*)alloc((size_t)NH_ * T_ * T_ * 2);
  u16*  o_attn  = (u16*)alloc((size_t)T_ * H_ * 2);
  float* x1     = (float*)alloc((size_t)T_ * H_ * 4);
  float* h2f    = (float*)alloc((size_t)T_ * H_ * 4);
  u16*  h2b     = (u16*)alloc((size_t)T_ * H_ * 2);
  u16*  gub     = (u16*)alloc((size_t)T_ * 2 * I_ * 2);
  u16*  actsh   = (u16*)alloc((size_t)T_ * I_ * 2);
  float* logits = (float*)alloc((size_t)T_ * E_ * 4);
  int*  topi    = (int*)alloc((size_t)T_ * TOPK_ * 4);
  float* topw   = (float*)alloc((size_t)T_ * TOPK_ * 4);
  int*  cnt     = (int*)alloc(E_ * 4);
  int*  eoffp   = (int*)alloc((E_ + 1) * 4);
  int*  cursor  = (int*)alloc(E_ * 4);
  int*  slots   = (int*)alloc((size_t)T_ * TOPK_ * 4);
  float* slotw  = (float*)alloc((size_t)T_ * TOPK_ * 4);
  u16*  g_g     = (u16*)alloc((size_t)T_ * TOPK_ * I_ * 2);
  u16*  u_g     = (u16*)alloc((size_t)T_ * TOPK_ * I_ * 2);
  u16*  a_g     = (u16*)alloc((size_t)T_ * TOPK_ * I_ * 2);
  float* routed = (float*)alloc((size_t)T_ * H_ * 4);

  hipMemsetAsync(routed, 0, (size_t)T_ * H_ * 4, stream);
  hipMemsetAsync(cnt, 0, E_ * 4, stream);

  // 1. h = rmsnorm(x, w_rms1)
  rmsnorm_k<<<T_, 256, 0, stream>>>(x, w_rms1, h1b, nullptr);

  // 2. qkv = h @ w_qkv.T   (M=1024 N=3072 K=2048)
  gemm_k<float, true, false, false, 0><<<dim3(8, 24, 1), 256, 0, stream>>>(
      h1b, w_qkv, qkvb, nullptr, nullptr, nullptr,
      T_, QKVN_, H_, H_, H_, QKVN_, 1.f, 0, 1, nullptr, nullptr, nullptr, 0, 0, 0, 1);

  // 3. RoPE + unpack
  rope_k<<<T_, 256, 0, stream>>>(qkvb, positions, q_r, k_r, v_r);

  // 4. scores = scale * q @ k^T per head (causal block-skip)
  gemm_k<u16, true, false, false, 1><<<dim3(8, 8, NH_), 256, 0, stream>>>(
      q_r, k_r, scoresP, nullptr, nullptr, nullptr,
      T_, T_, HD_, HD_, HD_, T_, SCALE_, 1, 1, nullptr, nullptr, nullptr,
      (long long)T_ * HD_, (long long)T_ * HD_, (long long)T_ * T_, NH_ / NKV_);

  // 5. masked softmax rows (in place, bf16)
  softmax_k<<<NH_ * T_, 64, 0, stream>>>(scoresP);

  // 6. o = P @ V per head  (B is [k=s][n=d] layout)
  gemm_k<u16, false, false, false, 0><<<dim3(8, 1, NH_), 256, 0, stream>>>(
      scoresP, v_r, o_attn, nullptr, nullptr, nullptr,
      T_, HD_, T_, T_, HD_, H_, 1.f, 0, 1, nullptr, nullptr, nullptr,
      (long long)T_ * T_, (long long)T_ * HD_, (long long)HD_, NH_ / NKV_);

  // 7. x1 = x + o @ w_o.T
  gemm_k<float, true, false, false, 2><<<dim3(8, 16, 1), 256, 0, stream>>>(
      o_attn, w_o, nullptr, x1, x, nullptr,
      T_, H_, H_, H_, H_, H_, 1.f, 0, 1, nullptr, nullptr, nullptr, 0, 0, 0, 1);

  // 8. h2 = rmsnorm(x1, w_rms2)  (f32 for router + bf16 for GEMMs)
  rmsnorm_k<<<T_, 256, 0, stream>>>(x1, w_rms2, h2b, h2f);

  // 9. router logits, top-k, grouping
  router_k<<<T_ * E_, 64, 0, stream>>>(h2f, w_router, logits);
  topk_k<<<4, 256, 0, stream>>>(logits, topi, topw);
  hist_k<<<16, 256, 0, stream>>>(topi, cnt);
  scan_k<<<1, 64, 0, stream>>>(cnt, eoffp, cursor);
  scatter_k<<<16, 256, 0, stream>>>(topi, topw, cursor, slots, slotw);

  // 10. grouped up: g = X_e @ w1[e], u = X_e @ w3[e]  (B is [k=h][n=i])
  gemm_k<float, false, true, true, 0><<<dim3(E_ * 8, 8, 1), 256, 0, stream>>>(
      h2b, w1, g_g, nullptr, nullptr, nullptr,
      0, I_, H_, H_, I_, I_, 1.f, 0, 8, eoffp, slots, nullptr,
      0, (long long)H_ * I_, 0, 1);
  gemm_k<float, false, true, true, 0><<<dim3(E_ * 8, 8, 1), 256, 0, stream>>>(
      h2b, w3, u_g, nullptr, nullptr, nullptr,
      0, I_, H_, H_, I_, I_, 1.f, 0, 8, eoffp, slots, nullptr,
      0, (long long)H_ * I_, 0, 1);
  silumul_k<<<(T_ * TOPK_ * I_) / (256 * 8), 256, 0, stream>>>(g_g, u_g, a_g);

  // 11. grouped down: routed[t] += w * (a_e @ w2[e])   (B is [k=i][n=h])
  gemm_k<float, false, true, false, 3><<<dim3(E_ * 8, 16, 1), 256, 0, stream>>>(
      a_g, w2, nullptr, routed, nullptr, nullptr,
      0, H_, I_, I_, H_, H_, 1.f, 0, 8, eoffp, slots, slotw,
      0, (long long)I_ * H_, 0, 1);

  // 12. shared expert: gu = h2 @ ws_gate_up.T ; act = silu(gs)*us
  gemm_k<float, true, false, false, 0><<<dim3(8, 16, 1), 256, 0, stream>>>(
      h2b, ws_gu, gub, nullptr, nullptr, nullptr,
      T_, 2 * I_, H_, H_, H_, 2 * I_, 1.f, 0, 1, nullptr, nullptr, nullptr, 0, 0, 0, 1);
  sharedact_k<<<(T_ * I_) / (256 * 8), 256, 0, stream>>>(gub, actsh);

  // 13. out = f32(x1 + routed + act @ ws_down.T)
  gemm_k<float, true, false, false, 4><<<dim3(8, 16, 1), 256, 0, stream>>>(
      actsh, ws_dn, nullptr, out, x1, routed,
      T_, H_, I_, I_, I_, H_, 1.f, 0, 1, nullptr, nullptr, nullptr, 0, 0, 0, 1);
}

// Round 3
// 1323.022 us; speedup vs baseline: 2.8673x; 2.8673x over previous
//
#include <hip/hip_runtime.h>
#include <hip/hip_bf16.h>
#include <math.h>
#include <stdint.h>

#define T_ 1024
#define H_ 2048
#define NH_ 16
#define NKV_ 4
#define HD_ 128
#define E_ 32
#define TOPK_ 4
#define I_ 1024
#define QKVN_ 3072
#define EPS_ 1e-6f
#define THETA_ 600000.0f
#define SCALE_ 0.08838834764831845f

typedef unsigned short u16;
typedef u16 u16x4 __attribute__((ext_vector_type(4)));
typedef u16 u16x8 __attribute__((ext_vector_type(8)));
typedef __bf16 bf16x8 __attribute__((ext_vector_type(8)));
typedef float f32x4 __attribute__((ext_vector_type(4)));

__device__ __forceinline__ u16 f2b(float f) {
  unsigned u = __builtin_bit_cast(unsigned, f);
  u += 0x7FFFu + ((u >> 16) & 1u);
  return (u16)(u >> 16);
}
__device__ __forceinline__ float b2f(u16 x) {
  unsigned u = ((unsigned)x) << 16;
  return __builtin_bit_cast(float, u);
}
// XOR swizzle (u16 units within a 64-wide row): involution, keeps 8-alignment
__device__ __forceinline__ int swz8(int r) { return ((r ^ (r >> 3)) & 7) << 3; }

// global -> LDS direct 16B (dest: wave-uniform base + lane*16)
__device__ __forceinline__ void gload16(const u16* g, u16* l) {
  __builtin_amdgcn_global_load_lds(
      reinterpret_cast<const __attribute__((address_space(1))) unsigned int*>(
          reinterpret_cast<uintptr_t>(g)),
      reinterpret_cast<__attribute__((address_space(3))) unsigned int*>(
          reinterpret_cast<uintptr_t>(l)),
      16, 0, 0);
}

// ---------------------------------------------------------------------------
// 128x128 (BK=64) bf16 MFMA GEMM, swizzled LDS, double-buffered 2-phase.
// A: bf16 bits [M][lda] (optional row gather via slots)
// B: BTL ? B[n][k] : B[k][n]; TB = float | u16
// causal: 0 none | 1 block-skip (scores) | 2 A-causal K-bound (PV)
// EPI: 0 bf16 store at (goff+row) | 1 bf16 store*alpha | 2 f32 res1+acc |
//      3 atomicAdd slotw*acc into Cf[token] | 4 f32 res1+res2+acc
// yhalf: fused second problem (B2/Cb2) on blockIdx.y >= yhalf (grouped only)
// ---------------------------------------------------------------------------
template<typename TB, bool BTL, bool GROUPED, bool GATHER, int EPI>
__global__ __launch_bounds__(256) void gemm_k(
    const u16* __restrict__ A, const TB* __restrict__ B, const TB* __restrict__ B2,
    u16* __restrict__ Cb, u16* __restrict__ Cb2, float* __restrict__ Cf,
    const float* __restrict__ res1, const float* __restrict__ res2,
    int M, int N, int K, int lda, int ldb, int ldc,
    float alpha, int causal, int mbmax, int yhalf,
    const int* __restrict__ eoff, const int* __restrict__ slots,
    const float* __restrict__ slotw,
    long long sAz, long long sBz, long long sCz, int bdivz)
{
  __shared__ u16 As[2][8192];
  __shared__ u16 Bs[2][8192];

  int m0, n0, Mloc, goff = 0;
  const u16* Ae = A;
  const TB* Be = B;
  u16* Cw = Cb;
  if (GROUPED) {
    int e = blockIdx.x / mbmax;
    int mb = blockIdx.x - e * mbmax;
    goff = eoff[e];
    Mloc = eoff[e + 1] - goff;
    m0 = mb * 128;
    if (m0 >= Mloc) return;
    int by = blockIdx.y;
    if (yhalf && by >= yhalf) {
      n0 = (by - yhalf) * 128;
      Be = B2 + (long long)e * sBz;
      Cw = Cb2;
    } else {
      n0 = by * 128;
      Be = B + (long long)e * sBz;
    }
    if (!GATHER) Ae = A + (long long)goff * lda;
  } else {
    m0 = blockIdx.x * 128;
    n0 = blockIdx.y * 128;
    Mloc = M;
    long long z = blockIdx.z;
    Ae = A + z * sAz;
    Be = B + (long long)(z / bdivz) * sBz;
    if (Cb) Cw = Cb + z * sCz;
    if (causal == 1 && n0 > m0 + 127) return;
  }

  const int tid = threadIdx.x;
  const int lane = tid & 63;
  const int wv = tid >> 6;
  const int wr = wv >> 1, wc = wv & 1;

  int kend = K;
  if (causal == 2) { int ke = m0 + 128; if (ke < kend) kend = ke; }

  f32x4 acc[4][4];
  #pragma unroll
  for (int i = 0; i < 4; ++i)
    #pragma unroll
    for (int j = 0; j < 4; ++j)
      acc[i][j] = f32x4{0.f, 0.f, 0.f, 0.f};

  // ---- staging helpers ----
  // A: global_load_lds with pre-swizzled source (swizzled layout, linear dest)
  auto stageA = [&](int bf, int k0) {
    #pragma unroll
    for (int it = 0; it < 4; ++it) {
      int r = it * 32 + (tid >> 3);
      int kk = (tid & 7) * 8;
      int rr = m0 + r;
      if (rr > Mloc - 1) rr = Mloc - 1;  // duplicate last row; masked at store
      long long row = GATHER ? (long long)slots[goff + rr] : (long long)rr;
      const u16* src = Ae + row * (long long)lda + k0 + (kk ^ swz8(r));
      gload16(src, &As[bf][it * 2048 + (tid & ~63) * 8]);
    }
  };

  // B register staging state (held across the MFMA phase)
  float4 bregT[8];   // BTL f32
  float brKN[32];    // [k][n] f32
  u16x8 bvKN[4];     // [k][n] u16

  auto loadB = [&](int bf, int k0) {
    if constexpr (BTL) {
      if constexpr (sizeof(TB) == 4) {
        const float* Bf = (const float*)Be;
        #pragma unroll
        for (int it = 0; it < 8; ++it) {
          int idx = it * 1024 + tid * 4;
          int n = idx >> 6, kk = idx & 63;
          bregT[it] = *(const float4*)(Bf + (long long)(n0 + n) * ldb + k0 + kk);
        }
      } else {
        // bf16 B[n][k]: direct global_load_lds, pre-swizzled source
        const u16* Bb = (const u16*)Be;
        #pragma unroll
        for (int it = 0; it < 4; ++it) {
          int r = it * 32 + (tid >> 3);
          int kk = (tid & 7) * 8;
          const u16* src = Bb + (long long)(n0 + r) * ldb + k0 + (kk ^ swz8(r));
          gload16(src, &Bs[bf][it * 2048 + (tid & ~63) * 8]);
        }
      }
    } else {
      if constexpr (sizeof(TB) == 4) {
        // f32 B[k][n]: per-lane dword columns (lanes cover consecutive n)
        const float* Bf = (const float*)Be;
        int n = (tid & 63) + ((tid >> 7) << 6);
        int ks = ((tid >> 6) & 1) * 32;
        const float* bp = Bf + (long long)(k0 + ks) * ldb + n0 + n;
        #pragma unroll
        for (int j = 0; j < 32; ++j) brKN[j] = bp[(long long)j * ldb];
      } else {
        // u16 B[k][n]: each thread 4k x 8n block
        const u16* Bb = (const u16*)Be;
        int nb = (tid & 15) * 8;
        int ks = (tid >> 4) * 4;
        #pragma unroll
        for (int i = 0; i < 4; ++i)
          bvKN[i] = *(const u16x8*)(Bb + (long long)(k0 + ks + i) * ldb + n0 + nb);
      }
    }
  };

  auto writeB = [&](int bf) {
    if constexpr (BTL) {
      if constexpr (sizeof(TB) == 4) {
        #pragma unroll
        for (int it = 0; it < 8; ++it) {
          int idx = it * 1024 + tid * 4;
          int n = idx >> 6, kk = idx & 63;
          float4 f = bregT[it];
          u16x4 o = u16x4{f2b(f.x), f2b(f.y), f2b(f.z), f2b(f.w)};
          *(u16x4*)(&Bs[bf][n * 64 + (kk ^ swz8(n))]) = o;
        }
      }
      // u16 BTL: nothing (gload_lds)
    } else {
      if constexpr (sizeof(TB) == 4) {
        int n = (tid & 63) + ((tid >> 7) << 6);
        int ks = ((tid >> 6) & 1) * 32;
        #pragma unroll
        for (int p = 0; p < 4; ++p) {
          u16x8 o;
          #pragma unroll
          for (int q = 0; q < 8; ++q) o[q] = f2b(brKN[p * 8 + q]);
          *(u16x8*)(&Bs[bf][n * 64 + ((ks + p * 8) ^ swz8(n))]) = o;
        }
      } else {
        int nb = (tid & 15) * 8;
        int ks = (tid >> 4) * 4;
        #pragma unroll
        for (int q = 0; q < 8; ++q) {
          int n = nb + q;
          u16x4 o = u16x4{bvKN[0][q], bvKN[1][q], bvKN[2][q], bvKN[3][q]};
          *(u16x4*)(&Bs[bf][n * 64 + (ks ^ swz8(n))]) = o;
        }
      }
    }
  };

  // per-lane fragment offsets + swizzle masks
  const int ar = (wr << 6) + (lane & 15);
  const int bc = (wc << 6) + (lane & 15);
  int aoff[4], asw[4], boff[4], bsw[4];
  #pragma unroll
  for (int m = 0; m < 4; ++m) {
    int r = ar + m * 16; aoff[m] = r * 64; asw[m] = swz8(r);
    int rb = bc + m * 16; boff[m] = rb * 64; bsw[m] = swz8(rb);
  }

  // ---- prologue ----
  stageA(0, 0);
  loadB(0, 0);
  writeB(0);
  __syncthreads();

  int buf = 0;
  for (int k0 = 0; k0 < kend; k0 += 64) {
    int nk = k0 + 64;
    bool more = nk < kend;
    if (more) { stageA(buf ^ 1, nk); loadB(buf ^ 1, nk); }
    // ---- MFMA on current buffer ----
    const u16* Ap = &As[buf][0];
    const u16* Bp = &Bs[buf][0];
    #pragma unroll
    for (int kk = 0; kk < 64; kk += 32) {
      int kb = kk + ((lane >> 4) << 3);
      bf16x8 af[4], bfr[4];
      #pragma unroll
      for (int m = 0; m < 4; ++m)
        af[m] = __builtin_bit_cast(bf16x8, *(const u16x8*)(Ap + aoff[m] + (kb ^ asw[m])));
      #pragma unroll
      for (int n = 0; n < 4; ++n)
        bfr[n] = __builtin_bit_cast(bf16x8, *(const u16x8*)(Bp + boff[n] + (kb ^ bsw[n])));
      #pragma unroll
      for (int m = 0; m < 4; ++m)
        #pragma unroll
        for (int n = 0; n < 4; ++n)
          acc[m][n] = __builtin_amdgcn_mfma_f32_16x16x32_bf16(af[m], bfr[n], acc[m][n], 0, 0, 0);
    }
    if (more) writeB(buf ^ 1);
    __syncthreads();
    buf ^= 1;
  }

  // ---- epilogue: C/D layout col=lane&15, row=(lane>>4)*4+j ----
  const int cr = lane & 15, rq = lane >> 4;
  #pragma unroll
  for (int m = 0; m < 4; ++m) {
    #pragma unroll
    for (int j = 0; j < 4; ++j) {
      int row = m0 + (wr << 6) + m * 16 + rq * 4 + j;
      if (row >= Mloc) continue;
      #pragma unroll
      for (int n = 0; n < 4; ++n) {
        int col = n0 + (wc << 6) + n * 16 + cr;
        float v = acc[m][n][j];
        long long o = (long long)(goff + row) * ldc + col;  // goff=0 if !GROUPED
        if constexpr (EPI == 0) {
          Cw[o] = f2b(v);
        } else if constexpr (EPI == 1) {
          Cw[o] = f2b(v * alpha);
        } else if constexpr (EPI == 2) {
          Cf[o] = res1[o] + v;
        } else if constexpr (EPI == 3) {
          int tok = slots[goff + row];
          float wgt = slotw[goff + row];
          atomicAdd(&Cf[(long long)tok * ldc + col], wgt * v);
        } else {
          Cf[o] = res1[o] + res2[o] + v;
        }
      }
    }
  }
}

// ---------------------------------------------------------------------------
__global__ __launch_bounds__(256) void rmsnorm_k(const float* __restrict__ x,
                                                 const float* __restrict__ w,
                                                 u16* __restrict__ outb,
                                                 float* __restrict__ outf) {
  int t = blockIdx.x;
  int tid = threadIdx.x;
  const float* xr = x + (long long)t * H_;
  float4 a = *(const float4*)(xr + tid * 8);
  float4 b = *(const float4*)(xr + tid * 8 + 4);
  float ss = a.x * a.x + a.y * a.y + a.z * a.z + a.w * a.w +
             b.x * b.x + b.y * b.y + b.z * b.z + b.w * b.w;
  #pragma unroll
  for (int o = 32; o; o >>= 1) ss += __shfl_down(ss, o);
  __shared__ float red[4];
  if ((tid & 63) == 0) red[tid >> 6] = ss;
  __syncthreads();
  float sc = rsqrtf((red[0] + red[1] + red[2] + red[3]) * (1.0f / H_) + EPS_);
  float vo[8] = {a.x, a.y, a.z, a.w, b.x, b.y, b.z, b.w};
  const float* wr = w + tid * 8;
  u16x8 ob;
  #pragma unroll
  for (int q = 0; q < 8; ++q) {
    float val = vo[q] * sc * wr[q];
    ob[q] = f2b(val);
    if (outf) outf[(long long)t * H_ + tid * 8 + q] = val;
  }
  *(u16x8*)(outb + (long long)t * H_ + tid * 8) = ob;
}

__global__ __launch_bounds__(256) void rope_k(const u16* __restrict__ qkv,
                                              const int* __restrict__ pos,
                                              u16* __restrict__ q_r,
                                              u16* __restrict__ k_r,
                                              u16* __restrict__ v_r) {
  int t = blockIdx.x;
  int tid = threadIdx.x;
  float p = (float)pos[t];
  const u16* row = qkv + (long long)t * QKVN_;
  const float cfac = logf(THETA_) * (1.0f / 64.0f);
  #pragma unroll
  for (int it = 0; it < 4; ++it) {
    int item = it * 256 + tid;
    int h = item >> 6, d = item & 63;
    float inv = expf(-cfac * (float)d);
    float ang = p * inv;
    float c = cosf(ang), s = sinf(ang);
    float x1v = b2f(row[h * 128 + d]);
    float x2v = b2f(row[h * 128 + 64 + d]);
    u16* dst = q_r + ((long long)h * T_ + t) * HD_;
    dst[d] = f2b(x1v * c - x2v * s);
    dst[d + 64] = f2b(x1v * s + x2v * c);
  }
  {
    int item = tid;
    int kv = item >> 6, d = item & 63;
    float inv = expf(-cfac * (float)d);
    float ang = p * inv;
    float c = cosf(ang), s = sinf(ang);
    float x1v = b2f(row[NH_ * HD_ + kv * 128 + d]);
    float x2v = b2f(row[NH_ * HD_ + kv * 128 + 64 + d]);
    u16* dst = k_r + ((long long)kv * T_ + t) * HD_;
    dst[d] = f2b(x1v * c - x2v * s);
    dst[d + 64] = f2b(x1v * s + x2v * c);
  }
  #pragma unroll
  for (int it = 0; it < 2; ++it) {
    int item = it * 256 + tid;
    int kv = item >> 7, d = item & 127;
    v_r[((long long)kv * T_ + t) * HD_ + d] = row[(NH_ + NKV_) * HD_ + kv * 128 + d];
  }
}

__global__ __launch_bounds__(64) void softmax_k(u16* __restrict__ P) {
  int r = blockIdx.x;
  int h = r >> 10, i = r & 1023;
  u16* row = P + ((long long)h * T_ + i) * T_;
  int lane = threadIdx.x;
  int n = i + 1;
  float vals[16];
  float mx = -1e30f;
  #pragma unroll
  for (int it = 0; it < 16; ++it) {
    int j = it * 64 + lane;
    float s = (j < n) ? b2f(row[j]) : -1e30f;
    vals[it] = s;
    mx = fmaxf(mx, s);
  }
  #pragma unroll
  for (int o = 32; o; o >>= 1) mx = fmaxf(mx, __shfl_xor(mx, o));
  float sum = 0.f;
  #pragma unroll
  for (int it = 0; it < 16; ++it) {
    int j = it * 64 + lane;
    float e = (j < n) ? __expf(vals[it] - mx) : 0.f;
    vals[it] = e;
    sum += e;
  }
  #pragma unroll
  for (int o = 32; o; o >>= 1) sum += __shfl_xor(sum, o);
  float inv = 1.f / sum;
  #pragma unroll
  for (int it = 0; it < 16; ++it) {
    int j = it * 64 + lane;
    row[j] = f2b(vals[it] * inv);
  }
}

__global__ __launch_bounds__(64) void router_k(const float* __restrict__ h2,
                                               const float* __restrict__ wr,
                                               float* __restrict__ logits) {
  int b = blockIdx.x;
  int t = b >> 5, e = b & 31;
  const float* xr = h2 + (long long)t * H_;
  const float* wv = wr + (long long)e * H_;
  int lane = threadIdx.x;
  float s = 0.f;
  #pragma unroll
  for (int it = 0; it < 8; ++it) {
    int h = it * 256 + lane * 4;
    float4 a = *(const float4*)(xr + h);
    float4 w4 = *(const float4*)(wv + h);
    s += a.x * w4.x + a.y * w4.y + a.z * w4.z + a.w * w4.w;
  }
  #pragma unroll
  for (int o = 32; o; o >>= 1) s += __shfl_xor(s, o);
  if (lane == 0) logits[b] = s;
}

__global__ __launch_bounds__(256) void topk_k(const float* __restrict__ logits,
                                              int* __restrict__ topi,
                                              float* __restrict__ topw) {
  int t = blockIdx.x * 256 + threadIdx.x;
  if (t >= T_) return;
  float l[E_];
  #pragma unroll
  for (int e = 0; e < E_; ++e) l[e] = logits[t * E_ + e];
  int sel[TOPK_];
  float sv[TOPK_];
  unsigned used = 0;
  for (int j = 0; j < TOPK_; ++j) {
    float best = -1e30f;
    int bi = 0;
    for (int e = 0; e < E_; ++e) {
      if (used & (1u << e)) continue;
      if (l[e] > best) { best = l[e]; bi = e; }
    }
    used |= 1u << bi;
    sel[j] = bi;
    sv[j] = best;
  }
  float mx = sv[0];
  float s = 0.f;
  #pragma unroll
  for (int j = 0; j < TOPK_; ++j) { sv[j] = __expf(sv[j] - mx); s += sv[j]; }
  float inv = 1.f / s;
  #pragma unroll
  for (int j = 0; j < TOPK_; ++j) {
    topi[t * TOPK_ + j] = sel[j];
    topw[t * TOPK_ + j] = sv[j] * inv;
  }
}

__global__ __launch_bounds__(256) void hist_k(const int* __restrict__ topi, int* __restrict__ cnt) {
  int idx = blockIdx.x * 256 + threadIdx.x;
  if (idx < T_ * TOPK_) atomicAdd(&cnt[topi[idx]], 1);
}

__global__ __launch_bounds__(64) void scan_k(const int* __restrict__ cnt,
                                             int* __restrict__ eoff,
                                             int* __restrict__ cursor) {
  if (threadIdx.x == 0) {
    int s = 0;
    for (int e = 0; e < E_; ++e) { eoff[e] = s; cursor[e] = s; s += cnt[e]; }
    eoff[E_] = s;
  }
}

__global__ __launch_bounds__(256) void scatter_k(const int* __restrict__ topi,
                                                 const float* __restrict__ topw,
                                                 int* __restrict__ cursor,
                                                 int* __restrict__ slots,
                                                 float* __restrict__ slotw) {
  int idx = blockIdx.x * 256 + threadIdx.x;
  if (idx >= T_ * TOPK_) return;
  int e = topi[idx];
  int pos = atomicAdd(&cursor[e], 1);
  slots[pos] = idx >> 2;
  slotw[pos] = topw[idx];
}

__global__ __launch_bounds__(256) void silumul_k(const u16* __restrict__ g,
                                                 const u16* __restrict__ u,
                                                 u16* __restrict__ a) {
  long long idx = ((long long)blockIdx.x * 256 + threadIdx.x) * 8;
  u16x8 gv = *(const u16x8*)(g + idx);
  u16x8 uv = *(const u16x8*)(u + idx);
  u16x8 o;
  #pragma unroll
  for (int q = 0; q < 8; ++q) {
    float x = b2f(gv[q]);
    float y = b2f(uv[q]);
    float sl = x / (1.f + __expf(-x));
    o[q] = f2b(sl * y);
  }
  *(u16x8*)(a + idx) = o;
}

__global__ __launch_bounds__(256) void sharedact_k(const u16* __restrict__ gu,
                                                   u16* __restrict__ act) {
  long long idx = ((long long)blockIdx.x * 256 + threadIdx.x) * 8;
  long long t = idx >> 10;
  int i = (int)(idx & 1023);
  const u16* row = gu + t * (2 * I_);
  u16x8 g = *(const u16x8*)(row + i);
  u16x8 u = *(const u16x8*)(row + I_ + i);
  u16x8 o;
  #pragma unroll
  for (int q = 0; q < 8; ++q) {
    float x = b2f(g[q]);
    float y = b2f(u[q]);
    float sl = x / (1.f + __expf(-x));
    o[q] = f2b(sl * y);
  }
  *(u16x8*)(act + t * I_ + i) = o;
}

// ---------------------------------------------------------------------------
extern "C" void kernel_launch(void* const* d_in, const int* in_sizes, int n_in,
                              void* d_out, int out_size, void* d_ws, size_t ws_size,
                              hipStream_t stream) {
  const float* x        = (const float*)d_in[0];
  const int* positions  = (const int*)d_in[1];
  const float* w_rms1   = (const float*)d_in[2];
  const float* w_rms2   = (const float*)d_in[3];
  const float* w_qkv    = (const float*)d_in[4];
  const float* w_o      = (const float*)d_in[5];
  const float* w_router = (const float*)d_in[6];
  const float* w1       = (const float*)d_in[7];
  const float* w3       = (const float*)d_in[8];
  const float* w2       = (const float*)d_in[9];
  const float* ws_gu    = (const float*)d_in[10];
  const float* ws_dn    = (const float*)d_in[11];
  float* out = (float*)d_out;

  char* ws = (char*)d_ws;
  size_t off = 0;
  auto alloc = [&](size_t bytes) {
    size_t o = off;
    off = (off + bytes + 255) & ~(size_t)255;
    return (void*)(ws + o);
  };
  u16*  h1b     = (u16*)alloc((size_t)T_ * H_ * 2);
  u16*  qkvb    = (u16*)alloc((size_t)T_ * QKVN_ * 2);
  u16*  q_r     = (u16*)alloc((size_t)NH_ * T_ * HD_ * 2);
  u16*  k_r     = (u16*)alloc((size_t)NKV_ * T_ * HD_ * 2);
  u16*  v_r     = (u16*)alloc((size_t)NKV_ * T_ * HD_ * 2);
  u16*  scoresP = (u16*)alloc((size_t)NH_ * T_ * T_ * 2);
  u16*  o_attn  = (u16*)alloc((size_t)T_ * H_ * 2);
  float* x1     = (float*)alloc((size_t)T_ * H_ * 4);
  float* h2f    = (float*)alloc((size_t)T_ * H_ * 4);
  u16*  h2b     = (u16*)alloc((size_t)T_ * H_ * 2);
  u16*  gub     = (u16*)alloc((size_t)T_ * 2 * I_ * 2);
  u16*  actsh   = (u16*)alloc((size_t)T_ * I_ * 2);
  float* logits = (float*)alloc((size_t)T_ * E_ * 4);
  int*  topi    = (int*)alloc((size_t)T_ * TOPK_ * 4);
  float* topw   = (float*)alloc((size_t)T_ * TOPK_ * 4);
  int*  cnt     = (int*)alloc(E_ * 4);
  int*  eoffp   = (int*)alloc((E_ + 1) * 4);
  int*  cursor  = (int*)alloc(E_ * 4);
  int*  slots   = (int*)alloc((size_t)T_ * TOPK_ * 4);
  float* slotw  = (float*)alloc((size_t)T_ * TOPK_ * 4);
  u16*  g_g     = (u16*)alloc((size_t)T_ * TOPK_ * I_ * 2);
  u16*  u_g     = (u16*)alloc((size_t)T_ * TOPK_ * I_ * 2);
  u16*  a_g     = (u16*)alloc((size_t)T_ * TOPK_ * I_ * 2);
  float* routed = (float*)alloc((size_t)T_ * H_ * 4);

  hipMemsetAsync(routed, 0, (size_t)T_ * H_ * 4, stream);
  hipMemsetAsync(cnt, 0, E_ * 4, stream);

  // 1. h = rmsnorm(x, w_rms1)
  rmsnorm_k<<<T_, 256, 0, stream>>>(x, w_rms1, h1b, nullptr);

  // 2. qkv = h @ w_qkv.T
  gemm_k<float, true, false, false, 0><<<dim3(8, 24, 1), 256, 0, stream>>>(
      h1b, w_qkv, nullptr, qkvb, nullptr, nullptr, nullptr, nullptr,
      T_, QKVN_, H_, H_, H_, QKVN_, 1.f, 0, 1, 0, nullptr, nullptr, nullptr, 0, 0, 0, 1);

  // 3. RoPE + unpack
  rope_k<<<T_, 256, 0, stream>>>(qkvb, positions, q_r, k_r, v_r);

  // 4. scores = scale * q @ k^T per head (causal block-skip)
  gemm_k<u16, true, false, false, 1><<<dim3(8, 8, NH_), 256, 0, stream>>>(
      q_r, k_r, nullptr, scoresP, nullptr, nullptr, nullptr, nullptr,
      T_, T_, HD_, HD_, HD_, T_, SCALE_, 1, 1, 0, nullptr, nullptr, nullptr,
      (long long)T_ * HD_, (long long)T_ * HD_, (long long)T_ * T_, NH_ / NKV_);

  // 5. masked softmax rows
  softmax_k<<<NH_ * T_, 64, 0, stream>>>(scoresP);

  // 6. o = P @ V per head (A-causal K bound)
  gemm_k<u16, false, false, false, 0><<<dim3(8, 1, NH_), 256, 0, stream>>>(
      scoresP, v_r, nullptr, o_attn, nullptr, nullptr, nullptr, nullptr,
      T_, HD_, T_, T_, HD_, H_, 1.f, 2, 1, 0, nullptr, nullptr, nullptr,
      (long long)T_ * T_, (long long)T_ * HD_, (long long)HD_, NH_ / NKV_);

  // 7. x1 = x + o @ w_o.T
  gemm_k<float, true, false, false, 2><<<dim3(8, 16, 1), 256, 0, stream>>>(
      o_attn, w_o, nullptr, nullptr, nullptr, x1, x, nullptr,
      T_, H_, H_, H_, H_, H_, 1.f, 0, 1, 0, nullptr, nullptr, nullptr, 0, 0, 0, 1);

  // 8. h2 = rmsnorm(x1, w_rms2)
  rmsnorm_k<<<T_, 256, 0, stream>>>(x1, w_rms2, h2b, h2f);

  // 9. router
  router_k<<<T_ * E_, 64, 0, stream>>>(h2f, w_router, logits);
  topk_k<<<4, 256, 0, stream>>>(logits, topi, topw);
  hist_k<<<16, 256, 0, stream>>>(topi, cnt);
  scan_k<<<1, 64, 0, stream>>>(cnt, eoffp, cursor);
  scatter_k<<<16, 256, 0, stream>>>(topi, topw, cursor, slots, slotw);

  // 10. fused grouped up: g = X_e @ w1[e] (y<8), u = X_e @ w3[e] (y>=8)
  gemm_k<float, false, true, true, 0><<<dim3(E_ * 8, 16, 1), 256, 0, stream>>>(
      h2b, w1, w3, g_g, u_g, nullptr, nullptr, nullptr,
      0, I_, H_, H_, I_, I_, 1.f, 0, 8, 8, eoffp, slots, nullptr,
      0, (long long)H_ * I_, 0, 1);
  silumul_k<<<(T_ * TOPK_ * I_) / (256 * 8), 256, 0, stream>>>(g_g, u_g, a_g);

  // 11. grouped down: routed[t] += w * (a_e @ w2[e])
  gemm_k<float, false, true, false, 3><<<dim3(E_ * 8, 16, 1), 256, 0, stream>>>(
      a_g, w2, nullptr, nullptr, nullptr, routed, nullptr, nullptr,
      0, H_, I_, I_, H_, H_, 1.f, 0, 8, 0, eoffp, slots, slotw,
      0, (long long)I_ * H_, 0, 1);

  // 12. shared expert
  gemm_k<float, true, false, false, 0><<<dim3(8, 16, 1), 256, 0, stream>>>(
      h2b, ws_gu, nullptr, gub, nullptr, nullptr, nullptr, nullptr,
      T_, 2 * I_, H_, H_, H_, 2 * I_, 1.f, 0, 1, 0, nullptr, nullptr, nullptr, 0, 0, 0, 1);
  sharedact_k<<<(T_ * I_) / (256 * 8), 256, 0, stream>>>(gub, actsh);

  // 13. out = f32(x1 + routed + act @ ws_down.T)
  gemm_k<float, true, false, false, 4><<<dim3(8, 16, 1), 256, 0, stream>>>(
      actsh, ws_dn, nullptr, nullptr, nullptr, out, x1, routed,
      T_, H_, I_, I_, I_, H_, 1.f, 0, 1, 0, nullptr, nullptr, nullptr, 0, 0, 0, 1);
}

// Round 4
// 942.504 us; speedup vs baseline: 4.0250x; 1.4037x over previous
//
#include <hip/hip_runtime.h>
#include <hip/hip_bf16.h>
#include <math.h>
#include <stdint.h>

#define T_ 1024
#define H_ 2048
#define NH_ 16
#define NKV_ 4
#define HD_ 128
#define E_ 32
#define TOPK_ 4
#define I_ 1024
#define QKVN_ 3072
#define EPS_ 1e-6f
#define THETA_ 600000.0f
#define SCALE_ 0.08838834764831845f

typedef unsigned short u16;
typedef u16 u16x4 __attribute__((ext_vector_type(4)));
typedef u16 u16x8 __attribute__((ext_vector_type(8)));
typedef __bf16 bf16x8 __attribute__((ext_vector_type(8)));
typedef float f32x4 __attribute__((ext_vector_type(4)));

__device__ __forceinline__ u16 f2b(float f) {
  unsigned u = __builtin_bit_cast(unsigned, f);
  u += 0x7FFFu + ((u >> 16) & 1u);
  return (u16)(u >> 16);
}
__device__ __forceinline__ float b2f(u16 x) {
  unsigned u = ((unsigned)x) << 16;
  return __builtin_bit_cast(float, u);
}
__device__ __forceinline__ int swz8(int r) { return ((r ^ (r >> 3)) & 7) << 3; }

__device__ __forceinline__ void gload16(const void* g, void* l) {
  __builtin_amdgcn_global_load_lds(
      reinterpret_cast<const __attribute__((address_space(1))) unsigned int*>(
          reinterpret_cast<uintptr_t>(g)),
      reinterpret_cast<__attribute__((address_space(3))) unsigned int*>(
          reinterpret_cast<uintptr_t>(l)),
      16, 0, 0);
}

// ---------------------------------------------------------------------------
// MoE grouped GEMM, M128 x N256 x BK32, split-K via blockIdx.z.
// B is f32 [k][n] expert-major; staged RAW f32 into LDS via global_load_lds
// (1 KB contiguous per wave-instruction), converted at fragment load.
// EPI 0: fused up (y<4 -> w1/O1, y>=4 -> w3/O2), atomicAdd f32 at slot row.
// EPI 1: down, atomicAdd slotw*acc into O1[token].
// ---------------------------------------------------------------------------
template<int EPI, bool GATHER>
__global__ __launch_bounds__(256) void moe_gemm_k(
    const u16* __restrict__ A, const float* __restrict__ B, const float* __restrict__ B2,
    float* __restrict__ O1, float* __restrict__ O2,
    int NW, int lda, int ldb, int kchunk,
    const int* __restrict__ eoff, const int* __restrict__ slots,
    const float* __restrict__ slotw, long long sBz)
{
  __shared__ u16 As[2][128 * 32];
  __shared__ float Bsf[2][32 * 256];

  const int e = blockIdx.x >> 2;
  const int mb = blockIdx.x & 3;
  const int goff = eoff[e];
  const int Mloc = eoff[e + 1] - goff;
  const int m0 = mb * 128;
  if (m0 >= Mloc) return;

  const int y = blockIdx.y;
  const float* Bp;
  float* Op;
  int n0;
  if constexpr (EPI == 0) {
    int wsel = y >> 2;
    n0 = (y & 3) * 256;
    Bp = (wsel ? B2 : B) + (long long)e * sBz;
    Op = wsel ? O2 : O1;
  } else {
    n0 = y * 256;
    Bp = B + (long long)e * sBz;
    Op = O1;
  }
  const int k0base = blockIdx.z * kchunk;
  const u16* Ae = GATHER ? A : (A + (long long)goff * lda);

  const int tid = threadIdx.x;
  const int lane = tid & 63;
  const int wv = tid >> 6;
  const int wm = wv >> 1, wn = wv & 1;

  f32x4 acc[4][8];
  #pragma unroll
  for (int m = 0; m < 4; ++m)
    #pragma unroll
    for (int n = 0; n < 8; ++n)
      acc[m][n] = f32x4{0.f, 0.f, 0.f, 0.f};

  // A: 128 rows x 32 k bf16, row-chunk-swizzled (2-bit XOR), via gload16
  auto stageA = [&](int bf, int k0) {
    #pragma unroll
    for (int it = 0; it < 2; ++it) {
      int r = it * 64 + (tid >> 2);
      int rr = m0 + r;
      if (rr > Mloc - 1) rr = Mloc - 1;
      long long row = GATHER ? (long long)slots[goff + rr] : (long long)rr;
      const u16* src = Ae + row * (long long)lda + k0 + (((tid & 3) ^ (r & 3)) << 3);
      gload16(src, &As[bf][it * 2048 + (tid & ~63) * 8]);
    }
  };
  // B: 32 k-rows x 256 n f32, linear, via gload16 (1 KB contiguous per wave op)
  auto stageB = [&](int bf, int k0) {
    #pragma unroll
    for (int p = 0; p < 8; ++p) {
      int k = p * 4 + (tid >> 6);
      const float* src = Bp + (long long)(k0 + k) * ldb + n0 + (tid & 63) * 4;
      gload16(src, &Bsf[bf][k * 256]);
    }
  };

  const int ar = wm * 64 + (lane & 15);
  const int kg = lane >> 4;          // k-group 0..3
  const int kb = kg << 3;            // k offset in elements
  const int cr = lane & 15;

  stageA(0, k0base);
  stageB(0, k0base);
  __syncthreads();

  int buf = 0;
  for (int ks = 0; ks < kchunk; ks += 32) {
    bool more = (ks + 32) < kchunk;
    if (more) { stageA(buf ^ 1, k0base + ks + 32); stageB(buf ^ 1, k0base + ks + 32); }
    const u16* Ap = &As[buf][0];
    const float* Bq = &Bsf[buf][0];
    bf16x8 af[4];
    #pragma unroll
    for (int m = 0; m < 4; ++m) {
      int r = ar + m * 16;
      af[m] = __builtin_bit_cast(bf16x8,
          *(const u16x8*)(Ap + r * 32 + ((kg ^ (r & 3)) << 3)));
    }
    #pragma unroll
    for (int n = 0; n < 8; ++n) {
      int nf = wn * 128 + n * 16 + cr;
      u16x8 bb;
      #pragma unroll
      for (int j = 0; j < 8; ++j) bb[j] = f2b(Bq[(kb + j) * 256 + nf]);
      bf16x8 bfr = __builtin_bit_cast(bf16x8, bb);
      #pragma unroll
      for (int m = 0; m < 4; ++m)
        acc[m][n] = __builtin_amdgcn_mfma_f32_16x16x32_bf16(af[m], bfr, acc[m][n], 0, 0, 0);
    }
    __syncthreads();
    buf ^= 1;
  }

  const int rq = lane >> 4;
  #pragma unroll
  for (int m = 0; m < 4; ++m) {
    #pragma unroll
    for (int j = 0; j < 4; ++j) {
      int row = m0 + wm * 64 + m * 16 + rq * 4 + j;
      if (row >= Mloc) continue;
      if constexpr (EPI == 0) {
        float* dst = Op + (long long)(goff + row) * NW;
        #pragma unroll
        for (int n = 0; n < 8; ++n) {
          int col = n0 + wn * 128 + n * 16 + cr;
          atomicAdd(dst + col, acc[m][n][j]);
        }
      } else {
        int tok = slots[goff + row];
        float wgt = slotw[goff + row];
        float* dst = Op + (long long)tok * NW;
        #pragma unroll
        for (int n = 0; n < 8; ++n) {
          int col = n0 + wn * 128 + n * 16 + cr;
          atomicAdd(dst + col, wgt * acc[m][n][j]);
        }
      }
    }
  }
}

// ---------------------------------------------------------------------------
// Generic 128x128 (BK=64) GEMM from round 3 (non-MoE uses only).
// ---------------------------------------------------------------------------
template<typename TB, bool BTL, bool GROUPED, bool GATHER, int EPI>
__global__ __launch_bounds__(256) void gemm_k(
    const u16* __restrict__ A, const TB* __restrict__ B, const TB* __restrict__ B2,
    u16* __restrict__ Cb, u16* __restrict__ Cb2, float* __restrict__ Cf,
    const float* __restrict__ res1, const float* __restrict__ res2,
    int M, int N, int K, int lda, int ldb, int ldc,
    float alpha, int causal, int mbmax, int yhalf,
    const int* __restrict__ eoff, const int* __restrict__ slots,
    const float* __restrict__ slotw,
    long long sAz, long long sBz, long long sCz, int bdivz)
{
  __shared__ u16 As[2][8192];
  __shared__ u16 Bs[2][8192];

  int m0, n0, Mloc, goff = 0;
  const u16* Ae = A;
  const TB* Be = B;
  u16* Cw = Cb;
  if (GROUPED) {
    int e = blockIdx.x / mbmax;
    int mb = blockIdx.x - e * mbmax;
    goff = eoff[e];
    Mloc = eoff[e + 1] - goff;
    m0 = mb * 128;
    if (m0 >= Mloc) return;
    int by = blockIdx.y;
    if (yhalf && by >= yhalf) {
      n0 = (by - yhalf) * 128;
      Be = B2 + (long long)e * sBz;
      Cw = Cb2;
    } else {
      n0 = by * 128;
      Be = B + (long long)e * sBz;
    }
    if (!GATHER) Ae = A + (long long)goff * lda;
  } else {
    m0 = blockIdx.x * 128;
    n0 = blockIdx.y * 128;
    Mloc = M;
    long long z = blockIdx.z;
    Ae = A + z * sAz;
    Be = B + (long long)(z / bdivz) * sBz;
    if (Cb) Cw = Cb + z * sCz;
    if (causal == 1 && n0 > m0 + 127) return;
  }

  const int tid = threadIdx.x;
  const int lane = tid & 63;
  const int wv = tid >> 6;
  const int wr = wv >> 1, wc = wv & 1;

  int kend = K;
  if (causal == 2) { int ke = m0 + 128; if (ke < kend) kend = ke; }

  f32x4 acc[4][4];
  #pragma unroll
  for (int i = 0; i < 4; ++i)
    #pragma unroll
    for (int j = 0; j < 4; ++j)
      acc[i][j] = f32x4{0.f, 0.f, 0.f, 0.f};

  auto stageA = [&](int bf, int k0) {
    #pragma unroll
    for (int it = 0; it < 4; ++it) {
      int r = it * 32 + (tid >> 3);
      int kk = (tid & 7) * 8;
      int rr = m0 + r;
      if (rr > Mloc - 1) rr = Mloc - 1;
      long long row = GATHER ? (long long)slots[goff + rr] : (long long)rr;
      const u16* src = Ae + row * (long long)lda + k0 + (kk ^ swz8(r));
      gload16(src, &As[bf][it * 2048 + (tid & ~63) * 8]);
    }
  };

  float4 bregT[8];
  float brKN[32];
  u16x8 bvKN[4];

  auto loadB = [&](int bf, int k0) {
    if constexpr (BTL) {
      if constexpr (sizeof(TB) == 4) {
        const float* Bf = (const float*)Be;
        #pragma unroll
        for (int it = 0; it < 8; ++it) {
          int idx = it * 1024 + tid * 4;
          int n = idx >> 6, kk = idx & 63;
          bregT[it] = *(const float4*)(Bf + (long long)(n0 + n) * ldb + k0 + kk);
        }
      } else {
        const u16* Bb = (const u16*)Be;
        #pragma unroll
        for (int it = 0; it < 4; ++it) {
          int r = it * 32 + (tid >> 3);
          int kk = (tid & 7) * 8;
          const u16* src = Bb + (long long)(n0 + r) * ldb + k0 + (kk ^ swz8(r));
          gload16(src, &Bs[bf][it * 2048 + (tid & ~63) * 8]);
        }
      }
    } else {
      if constexpr (sizeof(TB) == 4) {
        const float* Bf = (const float*)Be;
        int n = (tid & 63) + ((tid >> 7) << 6);
        int ks = ((tid >> 6) & 1) * 32;
        const float* bp = Bf + (long long)(k0 + ks) * ldb + n0 + n;
        #pragma unroll
        for (int j = 0; j < 32; ++j) brKN[j] = bp[(long long)j * ldb];
      } else {
        const u16* Bb = (const u16*)Be;
        int nb = (tid & 15) * 8;
        int ks = (tid >> 4) * 4;
        #pragma unroll
        for (int i = 0; i < 4; ++i)
          bvKN[i] = *(const u16x8*)(Bb + (long long)(k0 + ks + i) * ldb + n0 + nb);
      }
    }
  };

  auto writeB = [&](int bf) {
    if constexpr (BTL) {
      if constexpr (sizeof(TB) == 4) {
        #pragma unroll
        for (int it = 0; it < 8; ++it) {
          int idx = it * 1024 + tid * 4;
          int n = idx >> 6, kk = idx & 63;
          float4 f = bregT[it];
          u16x4 o = u16x4{f2b(f.x), f2b(f.y), f2b(f.z), f2b(f.w)};
          *(u16x4*)(&Bs[bf][n * 64 + (kk ^ swz8(n))]) = o;
        }
      }
    } else {
      if constexpr (sizeof(TB) == 4) {
        int n = (tid & 63) + ((tid >> 7) << 6);
        int ks = ((tid >> 6) & 1) * 32;
        #pragma unroll
        for (int p = 0; p < 4; ++p) {
          u16x8 o;
          #pragma unroll
          for (int q = 0; q < 8; ++q) o[q] = f2b(brKN[p * 8 + q]);
          *(u16x8*)(&Bs[bf][n * 64 + ((ks + p * 8) ^ swz8(n))]) = o;
        }
      } else {
        int nb = (tid & 15) * 8;
        int ks = (tid >> 4) * 4;
        #pragma unroll
        for (int q = 0; q < 8; ++q) {
          int n = nb + q;
          u16x4 o = u16x4{bvKN[0][q], bvKN[1][q], bvKN[2][q], bvKN[3][q]};
          *(u16x4*)(&Bs[bf][n * 64 + (ks ^ swz8(n))]) = o;
        }
      }
    }
  };

  const int ar = (wr << 6) + (lane & 15);
  const int bc = (wc << 6) + (lane & 15);
  int aoff[4], asw[4], boff[4], bsw[4];
  #pragma unroll
  for (int m = 0; m < 4; ++m) {
    int r = ar + m * 16; aoff[m] = r * 64; asw[m] = swz8(r);
    int rb = bc + m * 16; boff[m] = rb * 64; bsw[m] = swz8(rb);
  }

  stageA(0, 0);
  loadB(0, 0);
  writeB(0);
  __syncthreads();

  int buf = 0;
  for (int k0 = 0; k0 < kend; k0 += 64) {
    int nk = k0 + 64;
    bool more = nk < kend;
    if (more) { stageA(buf ^ 1, nk); loadB(buf ^ 1, nk); }
    const u16* Ap = &As[buf][0];
    const u16* Bp = &Bs[buf][0];
    #pragma unroll
    for (int kk = 0; kk < 64; kk += 32) {
      int kb = kk + ((lane >> 4) << 3);
      bf16x8 af[4], bfr[4];
      #pragma unroll
      for (int m = 0; m < 4; ++m)
        af[m] = __builtin_bit_cast(bf16x8, *(const u16x8*)(Ap + aoff[m] + (kb ^ asw[m])));
      #pragma unroll
      for (int n = 0; n < 4; ++n)
        bfr[n] = __builtin_bit_cast(bf16x8, *(const u16x8*)(Bp + boff[n] + (kb ^ bsw[n])));
      #pragma unroll
      for (int m = 0; m < 4; ++m)
        #pragma unroll
        for (int n = 0; n < 4; ++n)
          acc[m][n] = __builtin_amdgcn_mfma_f32_16x16x32_bf16(af[m], bfr[n], acc[m][n], 0, 0, 0);
    }
    if (more) writeB(buf ^ 1);
    __syncthreads();
    buf ^= 1;
  }

  const int cr = lane & 15, rq = lane >> 4;
  #pragma unroll
  for (int m = 0; m < 4; ++m) {
    #pragma unroll
    for (int j = 0; j < 4; ++j) {
      int row = m0 + (wr << 6) + m * 16 + rq * 4 + j;
      if (row >= Mloc) continue;
      #pragma unroll
      for (int n = 0; n < 4; ++n) {
        int col = n0 + (wc << 6) + n * 16 + cr;
        float v = acc[m][n][j];
        long long o = (long long)(goff + row) * ldc + col;
        if constexpr (EPI == 0) {
          Cw[o] = f2b(v);
        } else if constexpr (EPI == 1) {
          Cw[o] = f2b(v * alpha);
        } else if constexpr (EPI == 2) {
          Cf[o] = res1[o] + v;
        } else if constexpr (EPI == 3) {
          int tok = slots[goff + row];
          float wgt = slotw[goff + row];
          atomicAdd(&Cf[(long long)tok * ldc + col], wgt * v);
        } else {
          Cf[o] = res1[o] + res2[o] + v;
        }
      }
    }
  }
}

// ---------------------------------------------------------------------------
__global__ __launch_bounds__(256) void rmsnorm_k(const float* __restrict__ x,
                                                 const float* __restrict__ w,
                                                 u16* __restrict__ outb,
                                                 float* __restrict__ outf) {
  int t = blockIdx.x;
  int tid = threadIdx.x;
  const float* xr = x + (long long)t * H_;
  float4 a = *(const float4*)(xr + tid * 8);
  float4 b = *(const float4*)(xr + tid * 8 + 4);
  float ss = a.x * a.x + a.y * a.y + a.z * a.z + a.w * a.w +
             b.x * b.x + b.y * b.y + b.z * b.z + b.w * b.w;
  #pragma unroll
  for (int o = 32; o; o >>= 1) ss += __shfl_down(ss, o);
  __shared__ float red[4];
  if ((tid & 63) == 0) red[tid >> 6] = ss;
  __syncthreads();
  float sc = rsqrtf((red[0] + red[1] + red[2] + red[3]) * (1.0f / H_) + EPS_);
  float vo[8] = {a.x, a.y, a.z, a.w, b.x, b.y, b.z, b.w};
  const float* wr = w + tid * 8;
  u16x8 ob;
  #pragma unroll
  for (int q = 0; q < 8; ++q) {
    float val = vo[q] * sc * wr[q];
    ob[q] = f2b(val);
    if (outf) outf[(long long)t * H_ + tid * 8 + q] = val;
  }
  *(u16x8*)(outb + (long long)t * H_ + tid * 8) = ob;
}

__global__ __launch_bounds__(256) void rope_k(const u16* __restrict__ qkv,
                                              const int* __restrict__ pos,
                                              u16* __restrict__ q_r,
                                              u16* __restrict__ k_r,
                                              u16* __restrict__ v_r) {
  int t = blockIdx.x;
  int tid = threadIdx.x;
  float p = (float)pos[t];
  const u16* row = qkv + (long long)t * QKVN_;
  const float cfac = logf(THETA_) * (1.0f / 64.0f);
  #pragma unroll
  for (int it = 0; it < 4; ++it) {
    int item = it * 256 + tid;
    int h = item >> 6, d = item & 63;
    float inv = expf(-cfac * (float)d);
    float ang = p * inv;
    float c = cosf(ang), s = sinf(ang);
    float x1v = b2f(row[h * 128 + d]);
    float x2v = b2f(row[h * 128 + 64 + d]);
    u16* dst = q_r + ((long long)h * T_ + t) * HD_;
    dst[d] = f2b(x1v * c - x2v * s);
    dst[d + 64] = f2b(x1v * s + x2v * c);
  }
  {
    int item = tid;
    int kv = item >> 6, d = item & 63;
    float inv = expf(-cfac * (float)d);
    float ang = p * inv;
    float c = cosf(ang), s = sinf(ang);
    float x1v = b2f(row[NH_ * HD_ + kv * 128 + d]);
    float x2v = b2f(row[NH_ * HD_ + kv * 128 + 64 + d]);
    u16* dst = k_r + ((long long)kv * T_ + t) * HD_;
    dst[d] = f2b(x1v * c - x2v * s);
    dst[d + 64] = f2b(x1v * s + x2v * c);
  }
  #pragma unroll
  for (int it = 0; it < 2; ++it) {
    int item = it * 256 + tid;
    int kv = item >> 7, d = item & 127;
    v_r[((long long)kv * T_ + t) * HD_ + d] = row[(NH_ + NKV_) * HD_ + kv * 128 + d];
  }
}

__global__ __launch_bounds__(64) void softmax_k(u16* __restrict__ P) {
  int r = blockIdx.x;
  int h = r >> 10, i = r & 1023;
  u16* row = P + ((long long)h * T_ + i) * T_;
  int lane = threadIdx.x;
  int n = i + 1;
  float vals[16];
  float mx = -1e30f;
  #pragma unroll
  for (int it = 0; it < 16; ++it) {
    int j = it * 64 + lane;
    float s = (j < n) ? b2f(row[j]) : -1e30f;
    vals[it] = s;
    mx = fmaxf(mx, s);
  }
  #pragma unroll
  for (int o = 32; o; o >>= 1) mx = fmaxf(mx, __shfl_xor(mx, o));
  float sum = 0.f;
  #pragma unroll
  for (int it = 0; it < 16; ++it) {
    int j = it * 64 + lane;
    float e = (j < n) ? __expf(vals[it] - mx) : 0.f;
    vals[it] = e;
    sum += e;
  }
  #pragma unroll
  for (int o = 32; o; o >>= 1) sum += __shfl_xor(sum, o);
  float inv = 1.f / sum;
  #pragma unroll
  for (int it = 0; it < 16; ++it) {
    int j = it * 64 + lane;
    row[j] = f2b(vals[it] * inv);
  }
}

__global__ __launch_bounds__(64) void router_k(const float* __restrict__ h2,
                                               const float* __restrict__ wr,
                                               float* __restrict__ logits) {
  int b = blockIdx.x;
  int t = b >> 5, e = b & 31;
  const float* xr = h2 + (long long)t * H_;
  const float* wv = wr + (long long)e * H_;
  int lane = threadIdx.x;
  float s = 0.f;
  #pragma unroll
  for (int it = 0; it < 8; ++it) {
    int h = it * 256 + lane * 4;
    float4 a = *(const float4*)(xr + h);
    float4 w4 = *(const float4*)(wv + h);
    s += a.x * w4.x + a.y * w4.y + a.z * w4.z + a.w * w4.w;
  }
  #pragma unroll
  for (int o = 32; o; o >>= 1) s += __shfl_xor(s, o);
  if (lane == 0) logits[b] = s;
}

__global__ __launch_bounds__(256) void topk_k(const float* __restrict__ logits,
                                              int* __restrict__ topi,
                                              float* __restrict__ topw) {
  int t = blockIdx.x * 256 + threadIdx.x;
  if (t >= T_) return;
  float l[E_];
  #pragma unroll
  for (int e = 0; e < E_; ++e) l[e] = logits[t * E_ + e];
  int sel[TOPK_];
  float sv[TOPK_];
  unsigned used = 0;
  for (int j = 0; j < TOPK_; ++j) {
    float best = -1e30f;
    int bi = 0;
    for (int e = 0; e < E_; ++e) {
      if (used & (1u << e)) continue;
      if (l[e] > best) { best = l[e]; bi = e; }
    }
    used |= 1u << bi;
    sel[j] = bi;
    sv[j] = best;
  }
  float mx = sv[0];
  float s = 0.f;
  #pragma unroll
  for (int j = 0; j < TOPK_; ++j) { sv[j] = __expf(sv[j] - mx); s += sv[j]; }
  float inv = 1.f / s;
  #pragma unroll
  for (int j = 0; j < TOPK_; ++j) {
    topi[t * TOPK_ + j] = sel[j];
    topw[t * TOPK_ + j] = sv[j] * inv;
  }
}

__global__ __launch_bounds__(256) void hist_k(const int* __restrict__ topi, int* __restrict__ cnt) {
  int idx = blockIdx.x * 256 + threadIdx.x;
  if (idx < T_ * TOPK_) atomicAdd(&cnt[topi[idx]], 1);
}

__global__ __launch_bounds__(64) void scan_k(const int* __restrict__ cnt,
                                             int* __restrict__ eoff,
                                             int* __restrict__ cursor) {
  if (threadIdx.x == 0) {
    int s = 0;
    for (int e = 0; e < E_; ++e) { eoff[e] = s; cursor[e] = s; s += cnt[e]; }
    eoff[E_] = s;
  }
}

__global__ __launch_bounds__(256) void scatter_k(const int* __restrict__ topi,
                                                 const float* __restrict__ topw,
                                                 int* __restrict__ cursor,
                                                 int* __restrict__ slots,
                                                 float* __restrict__ slotw) {
  int idx = blockIdx.x * 256 + threadIdx.x;
  if (idx >= T_ * TOPK_) return;
  int e = topi[idx];
  int pos = atomicAdd(&cursor[e], 1);
  slots[pos] = idx >> 2;
  slotw[pos] = topw[idx];
}

// silu(g)*u from f32 split-K accumulators -> bf16
__global__ __launch_bounds__(256) void silumul_f_k(const float* __restrict__ g,
                                                   const float* __restrict__ u,
                                                   u16* __restrict__ a) {
  long long idx = ((long long)blockIdx.x * 256 + threadIdx.x) * 8;
  float4 g0 = *(const float4*)(g + idx);
  float4 g1 = *(const float4*)(g + idx + 4);
  float4 u0 = *(const float4*)(u + idx);
  float4 u1 = *(const float4*)(u + idx + 4);
  float gv[8] = {g0.x, g0.y, g0.z, g0.w, g1.x, g1.y, g1.z, g1.w};
  float uv[8] = {u0.x, u0.y, u0.z, u0.w, u1.x, u1.y, u1.z, u1.w};
  u16x8 o;
  #pragma unroll
  for (int q = 0; q < 8; ++q) {
    float x = gv[q];
    float sl = x / (1.f + __expf(-x));
    o[q] = f2b(sl * uv[q]);
  }
  *(u16x8*)(a + idx) = o;
}

__global__ __launch_bounds__(256) void sharedact_k(const u16* __restrict__ gu,
                                                   u16* __restrict__ act) {
  long long idx = ((long long)blockIdx.x * 256 + threadIdx.x) * 8;
  long long t = idx >> 10;
  int i = (int)(idx & 1023);
  const u16* row = gu + t * (2 * I_);
  u16x8 g = *(const u16x8*)(row + i);
  u16x8 u = *(const u16x8*)(row + I_ + i);
  u16x8 o;
  #pragma unroll
  for (int q = 0; q < 8; ++q) {
    float x = b2f(g[q]);
    float y = b2f(u[q]);
    float sl = x / (1.f + __expf(-x));
    o[q] = f2b(sl * y);
  }
  *(u16x8*)(act + t * I_ + i) = o;
}

// ---------------------------------------------------------------------------
extern "C" void kernel_launch(void* const* d_in, const int* in_sizes, int n_in,
                              void* d_out, int out_size, void* d_ws, size_t ws_size,
                              hipStream_t stream) {
  const float* x        = (const float*)d_in[0];
  const int* positions  = (const int*)d_in[1];
  const float* w_rms1   = (const float*)d_in[2];
  const float* w_rms2   = (const float*)d_in[3];
  const float* w_qkv    = (const float*)d_in[4];
  const float* w_o      = (const float*)d_in[5];
  const float* w_router = (const float*)d_in[6];
  const float* w1       = (const float*)d_in[7];
  const float* w3       = (const float*)d_in[8];
  const float* w2       = (const float*)d_in[9];
  const float* ws_gu    = (const float*)d_in[10];
  const float* ws_dn    = (const float*)d_in[11];
  float* out = (float*)d_out;

  char* ws = (char*)d_ws;
  size_t off = 0;
  auto alloc = [&](size_t bytes) {
    size_t o = off;
    off = (off + bytes + 255) & ~(size_t)255;
    return (void*)(ws + o);
  };
  u16*  h1b     = (u16*)alloc((size_t)T_ * H_ * 2);
  u16*  qkvb    = (u16*)alloc((size_t)T_ * QKVN_ * 2);
  u16*  q_r     = (u16*)alloc((size_t)NH_ * T_ * HD_ * 2);
  u16*  k_r     = (u16*)alloc((size_t)NKV_ * T_ * HD_ * 2);
  u16*  v_r     = (u16*)alloc((size_t)NKV_ * T_ * HD_ * 2);
  u16*  scoresP = (u16*)alloc((size_t)NH_ * T_ * T_ * 2);   // 33.5 MB; reused as g/u f32
  u16*  o_attn  = (u16*)alloc((size_t)T_ * H_ * 2);
  float* x1     = (float*)alloc((size_t)T_ * H_ * 4);
  float* h2f    = (float*)alloc((size_t)T_ * H_ * 4);
  u16*  h2b     = (u16*)alloc((size_t)T_ * H_ * 2);
  u16*  gub     = (u16*)alloc((size_t)T_ * 2 * I_ * 2);
  u16*  actsh   = (u16*)alloc((size_t)T_ * I_ * 2);
  float* logits = (float*)alloc((size_t)T_ * E_ * 4);
  int*  topi    = (int*)alloc((size_t)T_ * TOPK_ * 4);
  float* topw   = (float*)alloc((size_t)T_ * TOPK_ * 4);
  int*  cnt     = (int*)alloc(E_ * 4);
  int*  eoffp   = (int*)alloc((E_ + 1) * 4);
  int*  cursor  = (int*)alloc(E_ * 4);
  int*  slots   = (int*)alloc((size_t)T_ * TOPK_ * 4);
  float* slotw  = (float*)alloc((size_t)T_ * TOPK_ * 4);
  u16*  a_g     = (u16*)alloc((size_t)T_ * TOPK_ * I_ * 2);
  float* routed = (float*)alloc((size_t)T_ * H_ * 4);

  // f32 split-K accumulators aliased onto scoresP (dead after PV GEMM)
  float* g_f32 = (float*)scoresP;
  float* u_f32 = g_f32 + (size_t)T_ * TOPK_ * I_;

  hipMemsetAsync(routed, 0, (size_t)T_ * H_ * 4, stream);
  hipMemsetAsync(cnt, 0, E_ * 4, stream);

  // 1. h = rmsnorm(x, w_rms1)
  rmsnorm_k<<<T_, 256, 0, stream>>>(x, w_rms1, h1b, nullptr);

  // 2. qkv = h @ w_qkv.T
  gemm_k<float, true, false, false, 0><<<dim3(8, 24, 1), 256, 0, stream>>>(
      h1b, w_qkv, nullptr, qkvb, nullptr, nullptr, nullptr, nullptr,
      T_, QKVN_, H_, H_, H_, QKVN_, 1.f, 0, 1, 0, nullptr, nullptr, nullptr, 0, 0, 0, 1);

  // 3. RoPE + unpack
  rope_k<<<T_, 256, 0, stream>>>(qkvb, positions, q_r, k_r, v_r);

  // 4. scores = scale * q @ k^T per head (causal block-skip)
  gemm_k<u16, true, false, false, 1><<<dim3(8, 8, NH_), 256, 0, stream>>>(
      q_r, k_r, nullptr, scoresP, nullptr, nullptr, nullptr, nullptr,
      T_, T_, HD_, HD_, HD_, T_, SCALE_, 1, 1, 0, nullptr, nullptr, nullptr,
      (long long)T_ * HD_, (long long)T_ * HD_, (long long)T_ * T_, NH_ / NKV_);

  // 5. masked softmax rows
  softmax_k<<<NH_ * T_, 64, 0, stream>>>(scoresP);

  // 6. o = P @ V per head (A-causal K bound)
  gemm_k<u16, false, false, false, 0><<<dim3(8, 1, NH_), 256, 0, stream>>>(
      scoresP, v_r, nullptr, o_attn, nullptr, nullptr, nullptr, nullptr,
      T_, HD_, T_, T_, HD_, H_, 1.f, 2, 1, 0, nullptr, nullptr, nullptr,
      (long long)T_ * T_, (long long)T_ * HD_, (long long)HD_, NH_ / NKV_);

  // 7. x1 = x + o @ w_o.T
  gemm_k<float, true, false, false, 2><<<dim3(8, 16, 1), 256, 0, stream>>>(
      o_attn, w_o, nullptr, nullptr, nullptr, x1, x, nullptr,
      T_, H_, H_, H_, H_, H_, 1.f, 0, 1, 0, nullptr, nullptr, nullptr, 0, 0, 0, 1);

  // scoresP is dead now -> zero g/u split-K accumulators
  hipMemsetAsync(g_f32, 0, (size_t)T_ * TOPK_ * I_ * 8, stream);

  // 8. h2 = rmsnorm(x1, w_rms2)
  rmsnorm_k<<<T_, 256, 0, stream>>>(x1, w_rms2, h2b, h2f);

  // 9. router
  router_k<<<T_ * E_, 64, 0, stream>>>(h2f, w_router, logits);
  topk_k<<<4, 256, 0, stream>>>(logits, topi, topw);
  hist_k<<<16, 256, 0, stream>>>(topi, cnt);
  scan_k<<<1, 64, 0, stream>>>(cnt, eoffp, cursor);
  scatter_k<<<16, 256, 0, stream>>>(topi, topw, cursor, slots, slotw);

  // 10. fused grouped up (streaming): g += X_e @ w1[e], u += X_e @ w3[e]
  moe_gemm_k<0, true><<<dim3(E_ * 4, 8, 2), 256, 0, stream>>>(
      h2b, w1, w3, g_f32, u_f32,
      I_, H_, I_, 1024, eoffp, slots, nullptr, (long long)H_ * I_);
  silumul_f_k<<<(T_ * TOPK_ * I_) / (256 * 8), 256, 0, stream>>>(g_f32, u_f32, a_g);

  // 11. grouped down (streaming): routed[t] += w * (a_e @ w2[e])
  moe_gemm_k<1, false><<<dim3(E_ * 4, 8, 2), 256, 0, stream>>>(
      a_g, w2, nullptr, routed, nullptr,
      H_, I_, H_, 512, eoffp, slots, slotw, (long long)I_ * H_);

  // 12. shared expert
  gemm_k<float, true, false, false, 0><<<dim3(8, 16, 1), 256, 0, stream>>>(
      h2b, ws_gu, nullptr, gub, nullptr, nullptr, nullptr, nullptr,
      T_, 2 * I_, H_, H_, H_, 2 * I_, 1.f, 0, 1, 0, nullptr, nullptr, nullptr, 0, 0, 0, 1);
  sharedact_k<<<(T_ * I_) / (256 * 8), 256, 0, stream>>>(gub, actsh);

  // 13. out = f32(x1 + routed + act @ ws_down.T)
  gemm_k<float, true, false, false, 4><<<dim3(8, 16, 1), 256, 0, stream>>>(
      actsh, ws_dn, nullptr, nullptr, nullptr, out, x1, routed,
      T_, H_, I_, I_, I_, H_, 1.f, 0, 1, 0, nullptr, nullptr, nullptr, 0, 0, 0, 1);
}

// Round 5
// 923.093 us; speedup vs baseline: 4.1096x; 1.0210x over previous
//
#include <hip/hip_runtime.h>
#include <hip/hip_bf16.h>
#include <math.h>
#include <stdint.h>

#define T_ 1024
#define H_ 2048
#define NH_ 16
#define NKV_ 4
#define HD_ 128
#define E_ 32
#define TOPK_ 4
#define I_ 1024
#define QKVN_ 3072
#define EPS_ 1e-6f
#define THETA_ 600000.0f
#define SCALE_ 0.08838834764831845f

typedef unsigned short u16;
typedef u16 u16x4 __attribute__((ext_vector_type(4)));
typedef u16 u16x8 __attribute__((ext_vector_type(8)));
typedef __bf16 bf16x8 __attribute__((ext_vector_type(8)));
typedef float f32x4 __attribute__((ext_vector_type(4)));

__device__ __forceinline__ u16 f2b(float f) {
  unsigned u = __builtin_bit_cast(unsigned, f);
  u += 0x7FFFu + ((u >> 16) & 1u);
  return (u16)(u >> 16);
}
__device__ __forceinline__ float b2f(u16 x) {
  unsigned u = ((unsigned)x) << 16;
  return __builtin_bit_cast(float, u);
}
__device__ __forceinline__ int swz8(int r) { return ((r ^ (r >> 3)) & 7) << 3; }

__device__ __forceinline__ void gload16(const void* g, void* l) {
  __builtin_amdgcn_global_load_lds(
      reinterpret_cast<const __attribute__((address_space(1))) unsigned int*>(
          reinterpret_cast<uintptr_t>(g)),
      reinterpret_cast<__attribute__((address_space(3))) unsigned int*>(
          reinterpret_cast<uintptr_t>(l)),
      16, 0, 0);
}

// ---------------------------------------------------------------------------
// MoE grouped GEMM, M128 x N128 x BK32, split-K via blockIdx.z.
// 3-buffer LDS pipeline, 2 steps ahead, counted vmcnt (never drains to 0),
// raw s_barrier. Each wave issues exactly 6 global_load_lds per stage
// (A:2 + B:4); steady state 18 outstanding; wait vmcnt(12) = oldest stage.
// B staged RAW f32 (1KB contiguous per wave-inst), bit-4 XOR source
// pre-swizzle by (k>>3)&1 -> 2-way (free) column fragment reads.
// EPI 0: fused up (y<8 -> w1/O1, y>=8 -> w3/O2), atomicAdd at slot row.
// EPI 1: down, atomicAdd slotw*acc into O1[token].
// ---------------------------------------------------------------------------
template<int EPI, bool GATHER>
__global__ __launch_bounds__(256) void moe_gemm_k(
    const u16* __restrict__ A, const float* __restrict__ B, const float* __restrict__ B2,
    float* __restrict__ O1, float* __restrict__ O2,
    int NW, int lda, int ldb, int kchunk,
    const int* __restrict__ eoff, const int* __restrict__ slots,
    const float* __restrict__ slotw, long long sBz)
{
  __shared__ u16 As[3][128 * 32];
  __shared__ float Bsf[3][32 * 128];

  const int e = blockIdx.x >> 2;
  const int mb = blockIdx.x & 3;
  const int goff = eoff[e];
  const int Mloc = eoff[e + 1] - goff;
  const int m0 = mb * 128;
  if (m0 >= Mloc) return;

  const int y = blockIdx.y;
  const float* Bp;
  float* Op;
  int n0;
  if constexpr (EPI == 0) {
    int wsel = y >> 3;
    n0 = (y & 7) * 128;
    Bp = (wsel ? B2 : B) + (long long)e * sBz;
    Op = wsel ? O2 : O1;
  } else {
    n0 = y * 128;
    Bp = B + (long long)e * sBz;
    Op = O1;
  }
  const int k0base = blockIdx.z * kchunk;
  const u16* Ae = GATHER ? A : (A + (long long)goff * lda);

  const int tid = threadIdx.x;
  const int lane = tid & 63;
  const int wv = tid >> 6;
  const int wm = wv >> 1, wn = wv & 1;

  // per-thread A staging bases (2 rows; gather+clamp resolved once)
  const u16* Abase[2];
  #pragma unroll
  for (int it = 0; it < 2; ++it) {
    int r = it * 64 + wv * 16 + (lane >> 2);
    int rr = m0 + r;
    if (rr > Mloc - 1) rr = Mloc - 1;
    long long grow = GATHER ? (long long)slots[goff + rr] : (long long)rr;
    Abase[it] = Ae + grow * (long long)lda + (((lane & 3) ^ (r & 3)) << 3);
  }
  const int bcolA = 4 * (lane & 31);        // p even
  const int bcolB = bcolA ^ 16;             // p odd (bit-4 pre-swizzle)
  const int brow_sub = wv * 2 + (lane >> 5);

  const int nsteps = kchunk >> 5;

  f32x4 acc[4][4];
  #pragma unroll
  for (int m = 0; m < 4; ++m)
    #pragma unroll
    for (int n = 0; n < 4; ++n)
      acc[m][n] = f32x4{0.f, 0.f, 0.f, 0.f};

  auto stage = [&](int bf, int kt) {
    int k0 = k0base + (kt << 5);
    #pragma unroll
    for (int it = 0; it < 2; ++it)
      gload16(Abase[it] + k0, &As[bf][(it * 64 + wv * 16) * 32]);
    #pragma unroll
    for (int p = 0; p < 4; ++p) {
      int row = p * 8 + brow_sub;
      const float* src = Bp + (long long)(k0 + row) * ldb + n0 + ((p & 1) ? bcolB : bcolA);
      gload16(src, &Bsf[bf][(p * 8 + wv * 2) * 128]);
    }
  };

  stage(0, 0);
  stage(1, 1 < nsteps ? 1 : nsteps - 1);
  stage(2, 2 < nsteps ? 2 : nsteps - 1);

  const int kg = lane >> 4;
  const int cr = lane & 15;

  for (int t = 0; t < nsteps; ++t) {
    asm volatile("s_waitcnt vmcnt(12)" ::: "memory");
    __builtin_amdgcn_sched_barrier(0);
    __builtin_amdgcn_s_barrier();
    __builtin_amdgcn_sched_barrier(0);
    const int bf = t % 3;
    const u16* Ap = &As[bf][0];
    const float* Bq = &Bsf[bf][0];
    bf16x8 af[4];
    #pragma unroll
    for (int m = 0; m < 4; ++m) {
      int r = wm * 64 + m * 16 + cr;
      af[m] = __builtin_bit_cast(bf16x8,
          *(const u16x8*)(Ap + r * 32 + ((kg ^ (r & 3)) << 3)));
    }
    #pragma unroll
    for (int n = 0; n < 4; ++n) {
      int nfs = (wn * 64 + n * 16 + cr) ^ ((kg & 1) << 4);
      u16x8 bb;
      #pragma unroll
      for (int j = 0; j < 8; ++j) bb[j] = f2b(Bq[(kg * 8 + j) * 128 + nfs]);
      bf16x8 bfr = __builtin_bit_cast(bf16x8, bb);
      #pragma unroll
      for (int m = 0; m < 4; ++m)
        acc[m][n] = __builtin_amdgcn_mfma_f32_16x16x32_bf16(af[m], bfr, acc[m][n], 0, 0, 0);
    }
    __builtin_amdgcn_sched_barrier(0);
    __builtin_amdgcn_s_barrier();
    __builtin_amdgcn_sched_barrier(0);
    int kt = t + 3;
    if (kt >= nsteps) kt = nsteps - 1;   // tail: re-stage last (L2-hit), keeps counts exact
    stage(bf, kt);
  }

  const int rq = lane >> 4;
  #pragma unroll
  for (int m = 0; m < 4; ++m) {
    #pragma unroll
    for (int j = 0; j < 4; ++j) {
      int row = m0 + wm * 64 + m * 16 + rq * 4 + j;
      if (row >= Mloc) continue;
      if constexpr (EPI == 0) {
        float* dst = Op + (long long)(goff + row) * NW;
        #pragma unroll
        for (int n = 0; n < 4; ++n) {
          int col = n0 + wn * 64 + n * 16 + cr;
          atomicAdd(dst + col, acc[m][n][j]);
        }
      } else {
        int tok = slots[goff + row];
        float wgt = slotw[goff + row];
        float* dst = Op + (long long)tok * NW;
        #pragma unroll
        for (int n = 0; n < 4; ++n) {
          int col = n0 + wn * 64 + n * 16 + cr;
          atomicAdd(dst + col, wgt * acc[m][n][j]);
        }
      }
    }
  }
}

// ---------------------------------------------------------------------------
// Generic 128x128 (BK=64) GEMM (non-MoE uses).
// ---------------------------------------------------------------------------
template<typename TB, bool BTL, bool GROUPED, bool GATHER, int EPI>
__global__ __launch_bounds__(256) void gemm_k(
    const u16* __restrict__ A, const TB* __restrict__ B, const TB* __restrict__ B2,
    u16* __restrict__ Cb, u16* __restrict__ Cb2, float* __restrict__ Cf,
    const float* __restrict__ res1, const float* __restrict__ res2,
    int M, int N, int K, int lda, int ldb, int ldc,
    float alpha, int causal, int mbmax, int yhalf,
    const int* __restrict__ eoff, const int* __restrict__ slots,
    const float* __restrict__ slotw,
    long long sAz, long long sBz, long long sCz, int bdivz)
{
  __shared__ u16 As[2][8192];
  __shared__ u16 Bs[2][8192];

  int m0, n0, Mloc, goff = 0;
  const u16* Ae = A;
  const TB* Be = B;
  u16* Cw = Cb;
  if (GROUPED) {
    int e = blockIdx.x / mbmax;
    int mb = blockIdx.x - e * mbmax;
    goff = eoff[e];
    Mloc = eoff[e + 1] - goff;
    m0 = mb * 128;
    if (m0 >= Mloc) return;
    int by = blockIdx.y;
    if (yhalf && by >= yhalf) {
      n0 = (by - yhalf) * 128;
      Be = B2 + (long long)e * sBz;
      Cw = Cb2;
    } else {
      n0 = by * 128;
      Be = B + (long long)e * sBz;
    }
    if (!GATHER) Ae = A + (long long)goff * lda;
  } else {
    m0 = blockIdx.x * 128;
    n0 = blockIdx.y * 128;
    Mloc = M;
    long long z = blockIdx.z;
    Ae = A + z * sAz;
    Be = B + (long long)(z / bdivz) * sBz;
    if (Cb) Cw = Cb + z * sCz;
    if (causal == 1 && n0 > m0 + 127) return;
  }

  const int tid = threadIdx.x;
  const int lane = tid & 63;
  const int wv = tid >> 6;
  const int wr = wv >> 1, wc = wv & 1;

  int kend = K;
  if (causal == 2) { int ke = m0 + 128; if (ke < kend) kend = ke; }

  f32x4 acc[4][4];
  #pragma unroll
  for (int i = 0; i < 4; ++i)
    #pragma unroll
    for (int j = 0; j < 4; ++j)
      acc[i][j] = f32x4{0.f, 0.f, 0.f, 0.f};

  auto stageA = [&](int bf, int k0) {
    #pragma unroll
    for (int it = 0; it < 4; ++it) {
      int r = it * 32 + (tid >> 3);
      int kk = (tid & 7) * 8;
      int rr = m0 + r;
      if (rr > Mloc - 1) rr = Mloc - 1;
      long long row = GATHER ? (long long)slots[goff + rr] : (long long)rr;
      const u16* src = Ae + row * (long long)lda + k0 + (kk ^ swz8(r));
      gload16(src, &As[bf][it * 2048 + (tid & ~63) * 8]);
    }
  };

  float4 bregT[8];
  float brKN[32];
  u16x8 bvKN[4];

  auto loadB = [&](int bf, int k0) {
    if constexpr (BTL) {
      if constexpr (sizeof(TB) == 4) {
        const float* Bf = (const float*)Be;
        #pragma unroll
        for (int it = 0; it < 8; ++it) {
          int idx = it * 1024 + tid * 4;
          int n = idx >> 6, kk = idx & 63;
          bregT[it] = *(const float4*)(Bf + (long long)(n0 + n) * ldb + k0 + kk);
        }
      } else {
        const u16* Bb = (const u16*)Be;
        #pragma unroll
        for (int it = 0; it < 4; ++it) {
          int r = it * 32 + (tid >> 3);
          int kk = (tid & 7) * 8;
          const u16* src = Bb + (long long)(n0 + r) * ldb + k0 + (kk ^ swz8(r));
          gload16(src, &Bs[bf][it * 2048 + (tid & ~63) * 8]);
        }
      }
    } else {
      if constexpr (sizeof(TB) == 4) {
        const float* Bf = (const float*)Be;
        int n = (tid & 63) + ((tid >> 7) << 6);
        int ks = ((tid >> 6) & 1) * 32;
        const float* bp = Bf + (long long)(k0 + ks) * ldb + n0 + n;
        #pragma unroll
        for (int j = 0; j < 32; ++j) brKN[j] = bp[(long long)j * ldb];
      } else {
        const u16* Bb = (const u16*)Be;
        int nb = (tid & 15) * 8;
        int ks = (tid >> 4) * 4;
        #pragma unroll
        for (int i = 0; i < 4; ++i)
          bvKN[i] = *(const u16x8*)(Bb + (long long)(k0 + ks + i) * ldb + n0 + nb);
      }
    }
  };

  auto writeB = [&](int bf) {
    if constexpr (BTL) {
      if constexpr (sizeof(TB) == 4) {
        #pragma unroll
        for (int it = 0; it < 8; ++it) {
          int idx = it * 1024 + tid * 4;
          int n = idx >> 6, kk = idx & 63;
          float4 f = bregT[it];
          u16x4 o = u16x4{f2b(f.x), f2b(f.y), f2b(f.z), f2b(f.w)};
          *(u16x4*)(&Bs[bf][n * 64 + (kk ^ swz8(n))]) = o;
        }
      }
    } else {
      if constexpr (sizeof(TB) == 4) {
        int n = (tid & 63) + ((tid >> 7) << 6);
        int ks = ((tid >> 6) & 1) * 32;
        #pragma unroll
        for (int p = 0; p < 4; ++p) {
          u16x8 o;
          #pragma unroll
          for (int q = 0; q < 8; ++q) o[q] = f2b(brKN[p * 8 + q]);
          *(u16x8*)(&Bs[bf][n * 64 + ((ks + p * 8) ^ swz8(n))]) = o;
        }
      } else {
        int nb = (tid & 15) * 8;
        int ks = (tid >> 4) * 4;
        #pragma unroll
        for (int q = 0; q < 8; ++q) {
          int n = nb + q;
          u16x4 o = u16x4{bvKN[0][q], bvKN[1][q], bvKN[2][q], bvKN[3][q]};
          *(u16x4*)(&Bs[bf][n * 64 + (ks ^ swz8(n))]) = o;
        }
      }
    }
  };

  const int ar = (wr << 6) + (lane & 15);
  const int bc = (wc << 6) + (lane & 15);
  int aoff[4], asw[4], boff[4], bsw[4];
  #pragma unroll
  for (int m = 0; m < 4; ++m) {
    int r = ar + m * 16; aoff[m] = r * 64; asw[m] = swz8(r);
    int rb = bc + m * 16; boff[m] = rb * 64; bsw[m] = swz8(rb);
  }

  stageA(0, 0);
  loadB(0, 0);
  writeB(0);
  __syncthreads();

  int buf = 0;
  for (int k0 = 0; k0 < kend; k0 += 64) {
    int nk = k0 + 64;
    bool more = nk < kend;
    if (more) { stageA(buf ^ 1, nk); loadB(buf ^ 1, nk); }
    const u16* Ap = &As[buf][0];
    const u16* Bp = &Bs[buf][0];
    #pragma unroll
    for (int kk = 0; kk < 64; kk += 32) {
      int kb = kk + ((lane >> 4) << 3);
      bf16x8 af[4], bfr[4];
      #pragma unroll
      for (int m = 0; m < 4; ++m)
        af[m] = __builtin_bit_cast(bf16x8, *(const u16x8*)(Ap + aoff[m] + (kb ^ asw[m])));
      #pragma unroll
      for (int n = 0; n < 4; ++n)
        bfr[n] = __builtin_bit_cast(bf16x8, *(const u16x8*)(Bp + boff[n] + (kb ^ bsw[n])));
      #pragma unroll
      for (int m = 0; m < 4; ++m)
        #pragma unroll
        for (int n = 0; n < 4; ++n)
          acc[m][n] = __builtin_amdgcn_mfma_f32_16x16x32_bf16(af[m], bfr[n], acc[m][n], 0, 0, 0);
    }
    if (more) writeB(buf ^ 1);
    __syncthreads();
    buf ^= 1;
  }

  const int cr = lane & 15, rq = lane >> 4;
  #pragma unroll
  for (int m = 0; m < 4; ++m) {
    #pragma unroll
    for (int j = 0; j < 4; ++j) {
      int row = m0 + (wr << 6) + m * 16 + rq * 4 + j;
      if (row >= Mloc) continue;
      #pragma unroll
      for (int n = 0; n < 4; ++n) {
        int col = n0 + (wc << 6) + n * 16 + cr;
        float v = acc[m][n][j];
        long long o = (long long)(goff + row) * ldc + col;
        if constexpr (EPI == 0) {
          Cw[o] = f2b(v);
        } else if constexpr (EPI == 1) {
          Cw[o] = f2b(v * alpha);
        } else if constexpr (EPI == 2) {
          Cf[o] = res1[o] + v;
        } else if constexpr (EPI == 3) {
          int tok = slots[goff + row];
          float wgt = slotw[goff + row];
          atomicAdd(&Cf[(long long)tok * ldc + col], wgt * v);
        } else {
          Cf[o] = res1[o] + res2[o] + v;
        }
      }
    }
  }
}

// ---------------------------------------------------------------------------
__global__ __launch_bounds__(256) void rmsnorm_k(const float* __restrict__ x,
                                                 const float* __restrict__ w,
                                                 u16* __restrict__ outb,
                                                 float* __restrict__ outf) {
  int t = blockIdx.x;
  int tid = threadIdx.x;
  const float* xr = x + (long long)t * H_;
  float4 a = *(const float4*)(xr + tid * 8);
  float4 b = *(const float4*)(xr + tid * 8 + 4);
  float ss = a.x * a.x + a.y * a.y + a.z * a.z + a.w * a.w +
             b.x * b.x + b.y * b.y + b.z * b.z + b.w * b.w;
  #pragma unroll
  for (int o = 32; o; o >>= 1) ss += __shfl_down(ss, o);
  __shared__ float red[4];
  if ((tid & 63) == 0) red[tid >> 6] = ss;
  __syncthreads();
  float sc = rsqrtf((red[0] + red[1] + red[2] + red[3]) * (1.0f / H_) + EPS_);
  float vo[8] = {a.x, a.y, a.z, a.w, b.x, b.y, b.z, b.w};
  const float* wr = w + tid * 8;
  u16x8 ob;
  #pragma unroll
  for (int q = 0; q < 8; ++q) {
    float val = vo[q] * sc * wr[q];
    ob[q] = f2b(val);
    if (outf) outf[(long long)t * H_ + tid * 8 + q] = val;
  }
  *(u16x8*)(outb + (long long)t * H_ + tid * 8) = ob;
}

__global__ __launch_bounds__(256) void rope_k(const u16* __restrict__ qkv,
                                              const int* __restrict__ pos,
                                              u16* __restrict__ q_r,
                                              u16* __restrict__ k_r,
                                              u16* __restrict__ v_r) {
  int t = blockIdx.x;
  int tid = threadIdx.x;
  float p = (float)pos[t];
  const u16* row = qkv + (long long)t * QKVN_;
  const float cfac = logf(THETA_) * (1.0f / 64.0f);
  #pragma unroll
  for (int it = 0; it < 4; ++it) {
    int item = it * 256 + tid;
    int h = item >> 6, d = item & 63;
    float inv = expf(-cfac * (float)d);
    float ang = p * inv;
    float c = cosf(ang), s = sinf(ang);
    float x1v = b2f(row[h * 128 + d]);
    float x2v = b2f(row[h * 128 + 64 + d]);
    u16* dst = q_r + ((long long)h * T_ + t) * HD_;
    dst[d] = f2b(x1v * c - x2v * s);
    dst[d + 64] = f2b(x1v * s + x2v * c);
  }
  {
    int item = tid;
    int kv = item >> 6, d = item & 63;
    float inv = expf(-cfac * (float)d);
    float ang = p * inv;
    float c = cosf(ang), s = sinf(ang);
    float x1v = b2f(row[NH_ * HD_ + kv * 128 + d]);
    float x2v = b2f(row[NH_ * HD_ + kv * 128 + 64 + d]);
    u16* dst = k_r + ((long long)kv * T_ + t) * HD_;
    dst[d] = f2b(x1v * c - x2v * s);
    dst[d + 64] = f2b(x1v * s + x2v * c);
  }
  #pragma unroll
  for (int it = 0; it < 2; ++it) {
    int item = it * 256 + tid;
    int kv = item >> 7, d = item & 127;
    v_r[((long long)kv * T_ + t) * HD_ + d] = row[(NH_ + NKV_) * HD_ + kv * 128 + d];
  }
}

__global__ __launch_bounds__(64) void softmax_k(u16* __restrict__ P) {
  int r = blockIdx.x;
  int h = r >> 10, i = r & 1023;
  u16* row = P + ((long long)h * T_ + i) * T_;
  int lane = threadIdx.x;
  int n = i + 1;
  float vals[16];
  float mx = -1e30f;
  #pragma unroll
  for (int it = 0; it < 16; ++it) {
    int j = it * 64 + lane;
    float s = (j < n) ? b2f(row[j]) : -1e30f;
    vals[it] = s;
    mx = fmaxf(mx, s);
  }
  #pragma unroll
  for (int o = 32; o; o >>= 1) mx = fmaxf(mx, __shfl_xor(mx, o));
  float sum = 0.f;
  #pragma unroll
  for (int it = 0; it < 16; ++it) {
    int j = it * 64 + lane;
    float e = (j < n) ? __expf(vals[it] - mx) : 0.f;
    vals[it] = e;
    sum += e;
  }
  #pragma unroll
  for (int o = 32; o; o >>= 1) sum += __shfl_xor(sum, o);
  float inv = 1.f / sum;
  #pragma unroll
  for (int it = 0; it < 16; ++it) {
    int j = it * 64 + lane;
    row[j] = f2b(vals[it] * inv);
  }
}

__global__ __launch_bounds__(64) void router_k(const float* __restrict__ h2,
                                               const float* __restrict__ wr,
                                               float* __restrict__ logits) {
  int b = blockIdx.x;
  int t = b >> 5, e = b & 31;
  const float* xr = h2 + (long long)t * H_;
  const float* wv = wr + (long long)e * H_;
  int lane = threadIdx.x;
  float s = 0.f;
  #pragma unroll
  for (int it = 0; it < 8; ++it) {
    int h = it * 256 + lane * 4;
    float4 a = *(const float4*)(xr + h);
    float4 w4 = *(const float4*)(wv + h);
    s += a.x * w4.x + a.y * w4.y + a.z * w4.z + a.w * w4.w;
  }
  #pragma unroll
  for (int o = 32; o; o >>= 1) s += __shfl_xor(s, o);
  if (lane == 0) logits[b] = s;
}

__global__ __launch_bounds__(256) void topk_k(const float* __restrict__ logits,
                                              int* __restrict__ topi,
                                              float* __restrict__ topw) {
  int t = blockIdx.x * 256 + threadIdx.x;
  if (t >= T_) return;
  float l[E_];
  #pragma unroll
  for (int e = 0; e < E_; ++e) l[e] = logits[t * E_ + e];
  int sel[TOPK_];
  float sv[TOPK_];
  unsigned used = 0;
  for (int j = 0; j < TOPK_; ++j) {
    float best = -1e30f;
    int bi = 0;
    for (int e = 0; e < E_; ++e) {
      if (used & (1u << e)) continue;
      if (l[e] > best) { best = l[e]; bi = e; }
    }
    used |= 1u << bi;
    sel[j] = bi;
    sv[j] = best;
  }
  float mx = sv[0];
  float s = 0.f;
  #pragma unroll
  for (int j = 0; j < TOPK_; ++j) { sv[j] = __expf(sv[j] - mx); s += sv[j]; }
  float inv = 1.f / s;
  #pragma unroll
  for (int j = 0; j < TOPK_; ++j) {
    topi[t * TOPK_ + j] = sel[j];
    topw[t * TOPK_ + j] = sv[j] * inv;
  }
}

__global__ __launch_bounds__(256) void hist_k(const int* __restrict__ topi, int* __restrict__ cnt) {
  int idx = blockIdx.x * 256 + threadIdx.x;
  if (idx < T_ * TOPK_) atomicAdd(&cnt[topi[idx]], 1);
}

__global__ __launch_bounds__(64) void scan_k(const int* __restrict__ cnt,
                                             int* __restrict__ eoff,
                                             int* __restrict__ cursor) {
  if (threadIdx.x == 0) {
    int s = 0;
    for (int e = 0; e < E_; ++e) { eoff[e] = s; cursor[e] = s; s += cnt[e]; }
    eoff[E_] = s;
  }
}

__global__ __launch_bounds__(256) void scatter_k(const int* __restrict__ topi,
                                                 const float* __restrict__ topw,
                                                 int* __restrict__ cursor,
                                                 int* __restrict__ slots,
                                                 float* __restrict__ slotw) {
  int idx = blockIdx.x * 256 + threadIdx.x;
  if (idx >= T_ * TOPK_) return;
  int e = topi[idx];
  int pos = atomicAdd(&cursor[e], 1);
  slots[pos] = idx >> 2;
  slotw[pos] = topw[idx];
}

__global__ __launch_bounds__(256) void silumul_f_k(const float* __restrict__ g,
                                                   const float* __restrict__ u,
                                                   u16* __restrict__ a) {
  long long idx = ((long long)blockIdx.x * 256 + threadIdx.x) * 8;
  float4 g0 = *(const float4*)(g + idx);
  float4 g1 = *(const float4*)(g + idx + 4);
  float4 u0 = *(const float4*)(u + idx);
  float4 u1 = *(const float4*)(u + idx + 4);
  float gv[8] = {g0.x, g0.y, g0.z, g0.w, g1.x, g1.y, g1.z, g1.w};
  float uv[8] = {u0.x, u0.y, u0.z, u0.w, u1.x, u1.y, u1.z, u1.w};
  u16x8 o;
  #pragma unroll
  for (int q = 0; q < 8; ++q) {
    float x = gv[q];
    float sl = x / (1.f + __expf(-x));
    o[q] = f2b(sl * uv[q]);
  }
  *(u16x8*)(a + idx) = o;
}

__global__ __launch_bounds__(256) void sharedact_k(const u16* __restrict__ gu,
                                                   u16* __restrict__ act) {
  long long idx = ((long long)blockIdx.x * 256 + threadIdx.x) * 8;
  long long t = idx >> 10;
  int i = (int)(idx & 1023);
  const u16* row = gu + t * (2 * I_);
  u16x8 g = *(const u16x8*)(row + i);
  u16x8 u = *(const u16x8*)(row + I_ + i);
  u16x8 o;
  #pragma unroll
  for (int q = 0; q < 8; ++q) {
    float x = b2f(g[q]);
    float y = b2f(u[q]);
    float sl = x / (1.f + __expf(-x));
    o[q] = f2b(sl * y);
  }
  *(u16x8*)(act + t * I_ + i) = o;
}

// ---------------------------------------------------------------------------
extern "C" void kernel_launch(void* const* d_in, const int* in_sizes, int n_in,
                              void* d_out, int out_size, void* d_ws, size_t ws_size,
                              hipStream_t stream) {
  const float* x        = (const float*)d_in[0];
  const int* positions  = (const int*)d_in[1];
  const float* w_rms1   = (const float*)d_in[2];
  const float* w_rms2   = (const float*)d_in[3];
  const float* w_qkv    = (const float*)d_in[4];
  const float* w_o      = (const float*)d_in[5];
  const float* w_router = (const float*)d_in[6];
  const float* w1       = (const float*)d_in[7];
  const float* w3       = (const float*)d_in[8];
  const float* w2       = (const float*)d_in[9];
  const float* ws_gu    = (const float*)d_in[10];
  const float* ws_dn    = (const float*)d_in[11];
  float* out = (float*)d_out;

  char* ws = (char*)d_ws;
  size_t off = 0;
  auto alloc = [&](size_t bytes) {
    size_t o = off;
    off = (off + bytes + 255) & ~(size_t)255;
    return (void*)(ws + o);
  };
  u16*  h1b     = (u16*)alloc((size_t)T_ * H_ * 2);
  u16*  qkvb    = (u16*)alloc((size_t)T_ * QKVN_ * 2);
  u16*  q_r     = (u16*)alloc((size_t)NH_ * T_ * HD_ * 2);
  u16*  k_r     = (u16*)alloc((size_t)NKV_ * T_ * HD_ * 2);
  u16*  v_r     = (u16*)alloc((size_t)NKV_ * T_ * HD_ * 2);
  u16*  scoresP = (u16*)alloc((size_t)NH_ * T_ * T_ * 2);   // reused as g/u f32
  u16*  o_attn  = (u16*)alloc((size_t)T_ * H_ * 2);
  float* x1     = (float*)alloc((size_t)T_ * H_ * 4);
  float* h2f    = (float*)alloc((size_t)T_ * H_ * 4);
  u16*  h2b     = (u16*)alloc((size_t)T_ * H_ * 2);
  u16*  gub     = (u16*)alloc((size_t)T_ * 2 * I_ * 2);
  u16*  actsh   = (u16*)alloc((size_t)T_ * I_ * 2);
  float* logits = (float*)alloc((size_t)T_ * E_ * 4);
  int*  topi    = (int*)alloc((size_t)T_ * TOPK_ * 4);
  float* topw   = (float*)alloc((size_t)T_ * TOPK_ * 4);
  int*  cnt     = (int*)alloc(E_ * 4);
  int*  eoffp   = (int*)alloc((E_ + 1) * 4);
  int*  cursor  = (int*)alloc(E_ * 4);
  int*  slots   = (int*)alloc((size_t)T_ * TOPK_ * 4);
  float* slotw  = (float*)alloc((size_t)T_ * TOPK_ * 4);
  u16*  a_g     = (u16*)alloc((size_t)T_ * TOPK_ * I_ * 2);
  float* routed = (float*)alloc((size_t)T_ * H_ * 4);

  float* g_f32 = (float*)scoresP;
  float* u_f32 = g_f32 + (size_t)T_ * TOPK_ * I_;

  hipMemsetAsync(routed, 0, (size_t)T_ * H_ * 4, stream);
  hipMemsetAsync(cnt, 0, E_ * 4, stream);

  // 1. h = rmsnorm(x, w_rms1)
  rmsnorm_k<<<T_, 256, 0, stream>>>(x, w_rms1, h1b, nullptr);

  // 2. qkv = h @ w_qkv.T
  gemm_k<float, true, false, false, 0><<<dim3(8, 24, 1), 256, 0, stream>>>(
      h1b, w_qkv, nullptr, qkvb, nullptr, nullptr, nullptr, nullptr,
      T_, QKVN_, H_, H_, H_, QKVN_, 1.f, 0, 1, 0, nullptr, nullptr, nullptr, 0, 0, 0, 1);

  // 3. RoPE + unpack
  rope_k<<<T_, 256, 0, stream>>>(qkvb, positions, q_r, k_r, v_r);

  // 4. scores = scale * q @ k^T per head (causal block-skip)
  gemm_k<u16, true, false, false, 1><<<dim3(8, 8, NH_), 256, 0, stream>>>(
      q_r, k_r, nullptr, scoresP, nullptr, nullptr, nullptr, nullptr,
      T_, T_, HD_, HD_, HD_, T_, SCALE_, 1, 1, 0, nullptr, nullptr, nullptr,
      (long long)T_ * HD_, (long long)T_ * HD_, (long long)T_ * T_, NH_ / NKV_);

  // 5. masked softmax rows
  softmax_k<<<NH_ * T_, 64, 0, stream>>>(scoresP);

  // 6. o = P @ V per head (A-causal K bound)
  gemm_k<u16, false, false, false, 0><<<dim3(8, 1, NH_), 256, 0, stream>>>(
      scoresP, v_r, nullptr, o_attn, nullptr, nullptr, nullptr, nullptr,
      T_, HD_, T_, T_, HD_, H_, 1.f, 2, 1, 0, nullptr, nullptr, nullptr,
      (long long)T_ * T_, (long long)T_ * HD_, (long long)HD_, NH_ / NKV_);

  // 7. x1 = x + o @ w_o.T
  gemm_k<float, true, false, false, 2><<<dim3(8, 16, 1), 256, 0, stream>>>(
      o_attn, w_o, nullptr, nullptr, nullptr, x1, x, nullptr,
      T_, H_, H_, H_, H_, H_, 1.f, 0, 1, 0, nullptr, nullptr, nullptr, 0, 0, 0, 1);

  // scoresP dead -> zero g/u accumulators
  hipMemsetAsync(g_f32, 0, (size_t)T_ * TOPK_ * I_ * 8, stream);

  // 8. h2 = rmsnorm(x1, w_rms2)
  rmsnorm_k<<<T_, 256, 0, stream>>>(x1, w_rms2, h2b, h2f);

  // 9. router
  router_k<<<T_ * E_, 64, 0, stream>>>(h2f, w_router, logits);
  topk_k<<<4, 256, 0, stream>>>(logits, topi, topw);
  hist_k<<<16, 256, 0, stream>>>(topi, cnt);
  scan_k<<<1, 64, 0, stream>>>(cnt, eoffp, cursor);
  scatter_k<<<16, 256, 0, stream>>>(topi, topw, cursor, slots, slotw);

  // 10. fused grouped up: g += X_e @ w1[e] (y<8), u += X_e @ w3[e] (y>=8)
  moe_gemm_k<0, true><<<dim3(E_ * 4, 16, 2), 256, 0, stream>>>(
      h2b, w1, w3, g_f32, u_f32,
      I_, H_, I_, 1024, eoffp, slots, nullptr, (long long)H_ * I_);
  silumul_f_k<<<(T_ * TOPK_ * I_) / (256 * 8), 256, 0, stream>>>(g_f32, u_f32, a_g);

  // 11. grouped down: routed[t] += w * (a_e @ w2[e])
  moe_gemm_k<1, false><<<dim3(E_ * 4, 16, 2), 256, 0, stream>>>(
      a_g, w2, nullptr, routed, nullptr,
      H_, I_, H_, 512, eoffp, slots, slotw, (long long)I_ * H_);

  // 12. shared expert
  gemm_k<float, true, false, false, 0><<<dim3(8, 16, 1), 256, 0, stream>>>(
      h2b, ws_gu, nullptr, gub, nullptr, nullptr, nullptr, nullptr,
      T_, 2 * I_, H_, H_, H_, 2 * I_, 1.f, 0, 1, 0, nullptr, nullptr, nullptr, 0, 0, 0, 1);
  sharedact_k<<<(T_ * I_) / (256 * 8), 256, 0, stream>>>(gub, actsh);

  // 13. out = f32(x1 + routed + act @ ws_down.T)
  gemm_k<float, true, false, false, 4><<<dim3(8, 16, 1), 256, 0, stream>>>(
      actsh, ws_dn, nullptr, nullptr, nullptr, out, x1, routed,
      T_, H_, I_, I_, I_, H_, 1.f, 0, 1, 0, nullptr, nullptr, nullptr, 0, 0, 0, 1);
}

// Round 6
// 638.990 us; speedup vs baseline: 5.9368x; 1.4446x over previous
//
#include <hip/hip_runtime.h>
#include <hip/hip_bf16.h>
#include <math.h>
#include <stdint.h>

#define T_ 1024
#define H_ 2048
#define NH_ 16
#define NKV_ 4
#define HD_ 128
#define E_ 32
#define TOPK_ 4
#define I_ 1024
#define QKVN_ 3072
#define EPS_ 1e-6f
#define THETA_ 600000.0f
#define SCALE_ 0.08838834764831845f

typedef unsigned short u16;
typedef u16 u16x4 __attribute__((ext_vector_type(4)));
typedef u16 u16x8 __attribute__((ext_vector_type(8)));
typedef __bf16 bf16x8 __attribute__((ext_vector_type(8)));
typedef float f32x4 __attribute__((ext_vector_type(4)));

__device__ __forceinline__ u16 f2b(float f) {
  unsigned u = __builtin_bit_cast(unsigned, f);
  u += 0x7FFFu + ((u >> 16) & 1u);
  return (u16)(u >> 16);
}
__device__ __forceinline__ float b2f(u16 x) {
  unsigned u = ((unsigned)x) << 16;
  return __builtin_bit_cast(float, u);
}
__device__ __forceinline__ int swz8(int r) { return ((r ^ (r >> 3)) & 7) << 3; }

__device__ __forceinline__ void gload16(const void* g, void* l) {
  __builtin_amdgcn_global_load_lds(
      reinterpret_cast<const __attribute__((address_space(1))) unsigned int*>(
          reinterpret_cast<uintptr_t>(g)),
      reinterpret_cast<__attribute__((address_space(3))) unsigned int*>(
          reinterpret_cast<uintptr_t>(l)),
      16, 0, 0);
}

// ---------------------------------------------------------------------------
// MoE grouped GEMM, M64 x N128 x BK32, 512 threads (8 waves, 2m x 4n),
// 2-buffer LDS (40 KB) -> 3-4 blocks/CU = 24-32 waves/CU streaming.
// grid: x = nstripe (16), y = e*8 + mb, z = split-K (4).
// B staged RAW f32 via global_load_lds (1 KB contiguous per wave-inst),
// bit-4 XOR source pre-swizzle on odd 8-row k-groups; convert at frag load.
// EPI 0: fused up (x<8 -> w1/O1, x>=8 -> w3/O2), atomicAdd at slot row.
// EPI 1: down, atomicAdd slotw*acc into O1[token].
// ---------------------------------------------------------------------------
template<int EPI, bool GATHER>
__global__ __launch_bounds__(512, 6) void moe_gemm_k(
    const u16* __restrict__ A, const float* __restrict__ B, const float* __restrict__ B2,
    float* __restrict__ O1, float* __restrict__ O2,
    int NW, int lda, int ldb, int kchunk,
    const int* __restrict__ eoff, const int* __restrict__ slots,
    const float* __restrict__ slotw, long long sBz)
{
  __shared__ u16 As[2][64 * 32];
  __shared__ float Bsf[2][32 * 128];

  const int e = blockIdx.y >> 3;
  const int mb = blockIdx.y & 7;
  const int goff = eoff[e];
  const int Mloc = eoff[e + 1] - goff;
  const int m0 = mb * 64;
  if (m0 >= Mloc) return;

  const int xx = blockIdx.x;
  const float* Bp;
  float* Op;
  int n0;
  if constexpr (EPI == 0) {
    int wsel = xx >> 3;
    n0 = (xx & 7) * 128;
    Bp = (wsel ? B2 : B) + (long long)e * sBz;
    Op = wsel ? O2 : O1;
  } else {
    n0 = xx * 128;
    Bp = B + (long long)e * sBz;
    Op = O1;
  }
  const int k0base = blockIdx.z * kchunk;
  const u16* Ae = GATHER ? A : (A + (long long)goff * lda);

  const int tid = threadIdx.x;
  const int lane = tid & 63;
  const int wv = tid >> 6;           // 0..7
  const int wm = wv >> 2, wn = wv & 3;
  const int hl = lane >> 5;

  // A staging base (waves 0-3 only): 16 rows x 32k per wave-inst (1 KB)
  const u16* Abase = nullptr;
  if (wv < 4) {
    int r = wv * 16 + (lane >> 2);
    int rr = m0 + r;
    if (rr > Mloc - 1) rr = Mloc - 1;
    long long grow = GATHER ? (long long)slots[goff + rr] : (long long)rr;
    Abase = Ae + grow * (long long)lda + (((lane & 3) ^ (r & 3)) << 3);
  }
  // B: every wave stages 2 insts (2 k-rows each, 512 B/row contiguous)
  const int bcol = (4 * (lane & 31)) ^ ((wv >= 4) ? 16 : 0);  // f32 units

  f32x4 acc[2][2];
  #pragma unroll
  for (int m = 0; m < 2; ++m)
    #pragma unroll
    for (int n = 0; n < 2; ++n)
      acc[m][n] = f32x4{0.f, 0.f, 0.f, 0.f};

  auto stage = [&](int bf, int k0) {
    if (wv < 4) gload16(Abase + k0, &As[bf][wv * 512]);
    #pragma unroll
    for (int p = 0; p < 2; ++p) {
      int row = p * 16 + wv * 2 + hl;
      const float* src = Bp + (long long)(k0 + row) * ldb + n0 + bcol;
      gload16(src, &Bsf[bf][(p * 16 + wv * 2) * 128]);
    }
  };

  const int kg = lane >> 4;          // 0..3 (8-row k-group)
  const int cr = lane & 15;

  stage(0, k0base);
  __syncthreads();

  int buf = 0;
  for (int ks = 0; ks < kchunk; ks += 32) {
    bool more = (ks + 32) < kchunk;
    if (more) stage(buf ^ 1, k0base + ks + 32);
    const u16* Ap = &As[buf][0];
    const float* Bq = &Bsf[buf][0];
    bf16x8 af[2];
    #pragma unroll
    for (int m = 0; m < 2; ++m) {
      int r = wm * 32 + m * 16 + cr;
      af[m] = __builtin_bit_cast(bf16x8,
          *(const u16x8*)(Ap + r * 32 + ((kg ^ (r & 3)) << 3)));
    }
    #pragma unroll
    for (int n = 0; n < 2; ++n) {
      int nfs = (wn * 32 + n * 16 + cr) ^ ((kg & 1) << 4);
      u16x8 bb;
      #pragma unroll
      for (int j = 0; j < 8; ++j) bb[j] = f2b(Bq[(kg * 8 + j) * 128 + nfs]);
      bf16x8 bfr = __builtin_bit_cast(bf16x8, bb);
      #pragma unroll
      for (int m = 0; m < 2; ++m)
        acc[m][n] = __builtin_amdgcn_mfma_f32_16x16x32_bf16(af[m], bfr, acc[m][n], 0, 0, 0);
    }
    __syncthreads();
    buf ^= 1;
  }

  const int rq = lane >> 4;
  #pragma unroll
  for (int m = 0; m < 2; ++m) {
    #pragma unroll
    for (int j = 0; j < 4; ++j) {
      int row = m0 + wm * 32 + m * 16 + rq * 4 + j;
      if (row >= Mloc) continue;
      if constexpr (EPI == 0) {
        float* dst = Op + (long long)(goff + row) * NW;
        #pragma unroll
        for (int n = 0; n < 2; ++n) {
          int col = n0 + wn * 32 + n * 16 + cr;
          atomicAdd(dst + col, acc[m][n][j]);
        }
      } else {
        int tok = slots[goff + row];
        float wgt = slotw[goff + row];
        float* dst = Op + (long long)tok * NW;
        #pragma unroll
        for (int n = 0; n < 2; ++n) {
          int col = n0 + wn * 32 + n * 16 + cr;
          atomicAdd(dst + col, wgt * acc[m][n][j]);
        }
      }
    }
  }
}

// ---------------------------------------------------------------------------
// Generic 128x128 (BK=64) GEMM (non-MoE uses).
// ---------------------------------------------------------------------------
template<typename TB, bool BTL, bool GROUPED, bool GATHER, int EPI>
__global__ __launch_bounds__(256) void gemm_k(
    const u16* __restrict__ A, const TB* __restrict__ B, const TB* __restrict__ B2,
    u16* __restrict__ Cb, u16* __restrict__ Cb2, float* __restrict__ Cf,
    const float* __restrict__ res1, const float* __restrict__ res2,
    int M, int N, int K, int lda, int ldb, int ldc,
    float alpha, int causal, int mbmax, int yhalf,
    const int* __restrict__ eoff, const int* __restrict__ slots,
    const float* __restrict__ slotw,
    long long sAz, long long sBz, long long sCz, int bdivz)
{
  __shared__ u16 As[2][8192];
  __shared__ u16 Bs[2][8192];

  int m0, n0, Mloc, goff = 0;
  const u16* Ae = A;
  const TB* Be = B;
  u16* Cw = Cb;
  if (GROUPED) {
    int e = blockIdx.x / mbmax;
    int mb = blockIdx.x - e * mbmax;
    goff = eoff[e];
    Mloc = eoff[e + 1] - goff;
    m0 = mb * 128;
    if (m0 >= Mloc) return;
    int by = blockIdx.y;
    if (yhalf && by >= yhalf) {
      n0 = (by - yhalf) * 128;
      Be = B2 + (long long)e * sBz;
      Cw = Cb2;
    } else {
      n0 = by * 128;
      Be = B + (long long)e * sBz;
    }
    if (!GATHER) Ae = A + (long long)goff * lda;
  } else {
    m0 = blockIdx.x * 128;
    n0 = blockIdx.y * 128;
    Mloc = M;
    long long z = blockIdx.z;
    Ae = A + z * sAz;
    Be = B + (long long)(z / bdivz) * sBz;
    if (Cb) Cw = Cb + z * sCz;
    if (causal == 1 && n0 > m0 + 127) return;
  }

  const int tid = threadIdx.x;
  const int lane = tid & 63;
  const int wv = tid >> 6;
  const int wr = wv >> 1, wc = wv & 1;

  int kend = K;
  if (causal == 2) { int ke = m0 + 128; if (ke < kend) kend = ke; }

  f32x4 acc[4][4];
  #pragma unroll
  for (int i = 0; i < 4; ++i)
    #pragma unroll
    for (int j = 0; j < 4; ++j)
      acc[i][j] = f32x4{0.f, 0.f, 0.f, 0.f};

  auto stageA = [&](int bf, int k0) {
    #pragma unroll
    for (int it = 0; it < 4; ++it) {
      int r = it * 32 + (tid >> 3);
      int kk = (tid & 7) * 8;
      int rr = m0 + r;
      if (rr > Mloc - 1) rr = Mloc - 1;
      long long row = GATHER ? (long long)slots[goff + rr] : (long long)rr;
      const u16* src = Ae + row * (long long)lda + k0 + (kk ^ swz8(r));
      gload16(src, &As[bf][it * 2048 + (tid & ~63) * 8]);
    }
  };

  float4 bregT[8];
  float brKN[32];
  u16x8 bvKN[4];

  auto loadB = [&](int bf, int k0) {
    if constexpr (BTL) {
      if constexpr (sizeof(TB) == 4) {
        const float* Bf = (const float*)Be;
        #pragma unroll
        for (int it = 0; it < 8; ++it) {
          int idx = it * 1024 + tid * 4;
          int n = idx >> 6, kk = idx & 63;
          bregT[it] = *(const float4*)(Bf + (long long)(n0 + n) * ldb + k0 + kk);
        }
      } else {
        const u16* Bb = (const u16*)Be;
        #pragma unroll
        for (int it = 0; it < 4; ++it) {
          int r = it * 32 + (tid >> 3);
          int kk = (tid & 7) * 8;
          const u16* src = Bb + (long long)(n0 + r) * ldb + k0 + (kk ^ swz8(r));
          gload16(src, &Bs[bf][it * 2048 + (tid & ~63) * 8]);
        }
      }
    } else {
      if constexpr (sizeof(TB) == 4) {
        const float* Bf = (const float*)Be;
        int n = (tid & 63) + ((tid >> 7) << 6);
        int ks = ((tid >> 6) & 1) * 32;
        const float* bp = Bf + (long long)(k0 + ks) * ldb + n0 + n;
        #pragma unroll
        for (int j = 0; j < 32; ++j) brKN[j] = bp[(long long)j * ldb];
      } else {
        const u16* Bb = (const u16*)Be;
        int nb = (tid & 15) * 8;
        int ks = (tid >> 4) * 4;
        #pragma unroll
        for (int i = 0; i < 4; ++i)
          bvKN[i] = *(const u16x8*)(Bb + (long long)(k0 + ks + i) * ldb + n0 + nb);
      }
    }
  };

  auto writeB = [&](int bf) {
    if constexpr (BTL) {
      if constexpr (sizeof(TB) == 4) {
        #pragma unroll
        for (int it = 0; it < 8; ++it) {
          int idx = it * 1024 + tid * 4;
          int n = idx >> 6, kk = idx & 63;
          float4 f = bregT[it];
          u16x4 o = u16x4{f2b(f.x), f2b(f.y), f2b(f.z), f2b(f.w)};
          *(u16x4*)(&Bs[bf][n * 64 + (kk ^ swz8(n))]) = o;
        }
      }
    } else {
      if constexpr (sizeof(TB) == 4) {
        int n = (tid & 63) + ((tid >> 7) << 6);
        int ks = ((tid >> 6) & 1) * 32;
        #pragma unroll
        for (int p = 0; p < 4; ++p) {
          u16x8 o;
          #pragma unroll
          for (int q = 0; q < 8; ++q) o[q] = f2b(brKN[p * 8 + q]);
          *(u16x8*)(&Bs[bf][n * 64 + ((ks + p * 8) ^ swz8(n))]) = o;
        }
      } else {
        int nb = (tid & 15) * 8;
        int ks = (tid >> 4) * 4;
        #pragma unroll
        for (int q = 0; q < 8; ++q) {
          int n = nb + q;
          u16x4 o = u16x4{bvKN[0][q], bvKN[1][q], bvKN[2][q], bvKN[3][q]};
          *(u16x4*)(&Bs[bf][n * 64 + (ks ^ swz8(n))]) = o;
        }
      }
    }
  };

  const int ar = (wr << 6) + (lane & 15);
  const int bc = (wc << 6) + (lane & 15);
  int aoff[4], asw[4], boff[4], bsw[4];
  #pragma unroll
  for (int m = 0; m < 4; ++m) {
    int r = ar + m * 16; aoff[m] = r * 64; asw[m] = swz8(r);
    int rb = bc + m * 16; boff[m] = rb * 64; bsw[m] = swz8(rb);
  }

  stageA(0, 0);
  loadB(0, 0);
  writeB(0);
  __syncthreads();

  int buf = 0;
  for (int k0 = 0; k0 < kend; k0 += 64) {
    int nk = k0 + 64;
    bool more = nk < kend;
    if (more) { stageA(buf ^ 1, nk); loadB(buf ^ 1, nk); }
    const u16* Ap = &As[buf][0];
    const u16* Bp = &Bs[buf][0];
    #pragma unroll
    for (int kk = 0; kk < 64; kk += 32) {
      int kb = kk + ((lane >> 4) << 3);
      bf16x8 af[4], bfr[4];
      #pragma unroll
      for (int m = 0; m < 4; ++m)
        af[m] = __builtin_bit_cast(bf16x8, *(const u16x8*)(Ap + aoff[m] + (kb ^ asw[m])));
      #pragma unroll
      for (int n = 0; n < 4; ++n)
        bfr[n] = __builtin_bit_cast(bf16x8, *(const u16x8*)(Bp + boff[n] + (kb ^ bsw[n])));
      #pragma unroll
      for (int m = 0; m < 4; ++m)
        #pragma unroll
        for (int n = 0; n < 4; ++n)
          acc[m][n] = __builtin_amdgcn_mfma_f32_16x16x32_bf16(af[m], bfr[n], acc[m][n], 0, 0, 0);
    }
    if (more) writeB(buf ^ 1);
    __syncthreads();
    buf ^= 1;
  }

  const int cr = lane & 15, rq = lane >> 4;
  #pragma unroll
  for (int m = 0; m < 4; ++m) {
    #pragma unroll
    for (int j = 0; j < 4; ++j) {
      int row = m0 + (wr << 6) + m * 16 + rq * 4 + j;
      if (row >= Mloc) continue;
      #pragma unroll
      for (int n = 0; n < 4; ++n) {
        int col = n0 + (wc << 6) + n * 16 + cr;
        float v = acc[m][n][j];
        long long o = (long long)(goff + row) * ldc + col;
        if constexpr (EPI == 0) {
          Cw[o] = f2b(v);
        } else if constexpr (EPI == 1) {
          Cw[o] = f2b(v * alpha);
        } else if constexpr (EPI == 2) {
          Cf[o] = res1[o] + v;
        } else if constexpr (EPI == 3) {
          int tok = slots[goff + row];
          float wgt = slotw[goff + row];
          atomicAdd(&Cf[(long long)tok * ldc + col], wgt * v);
        } else {
          Cf[o] = res1[o] + res2[o] + v;
        }
      }
    }
  }
}

// ---------------------------------------------------------------------------
__global__ __launch_bounds__(256) void rmsnorm_k(const float* __restrict__ x,
                                                 const float* __restrict__ w,
                                                 u16* __restrict__ outb,
                                                 float* __restrict__ outf) {
  int t = blockIdx.x;
  int tid = threadIdx.x;
  const float* xr = x + (long long)t * H_;
  float4 a = *(const float4*)(xr + tid * 8);
  float4 b = *(const float4*)(xr + tid * 8 + 4);
  float ss = a.x * a.x + a.y * a.y + a.z * a.z + a.w * a.w +
             b.x * b.x + b.y * b.y + b.z * b.z + b.w * b.w;
  #pragma unroll
  for (int o = 32; o; o >>= 1) ss += __shfl_down(ss, o);
  __shared__ float red[4];
  if ((tid & 63) == 0) red[tid >> 6] = ss;
  __syncthreads();
  float sc = rsqrtf((red[0] + red[1] + red[2] + red[3]) * (1.0f / H_) + EPS_);
  float vo[8] = {a.x, a.y, a.z, a.w, b.x, b.y, b.z, b.w};
  const float* wr = w + tid * 8;
  u16x8 ob;
  #pragma unroll
  for (int q = 0; q < 8; ++q) {
    float val = vo[q] * sc * wr[q];
    ob[q] = f2b(val);
    if (outf) outf[(long long)t * H_ + tid * 8 + q] = val;
  }
  *(u16x8*)(outb + (long long)t * H_ + tid * 8) = ob;
}

__global__ __launch_bounds__(256) void rope_k(const u16* __restrict__ qkv,
                                              const int* __restrict__ pos,
                                              u16* __restrict__ q_r,
                                              u16* __restrict__ k_r,
                                              u16* __restrict__ v_r) {
  int t = blockIdx.x;
  int tid = threadIdx.x;
  float p = (float)pos[t];
  const u16* row = qkv + (long long)t * QKVN_;
  const float cfac = logf(THETA_) * (1.0f / 64.0f);
  #pragma unroll
  for (int it = 0; it < 4; ++it) {
    int item = it * 256 + tid;
    int h = item >> 6, d = item & 63;
    float inv = expf(-cfac * (float)d);
    float ang = p * inv;
    float c = cosf(ang), s = sinf(ang);
    float x1v = b2f(row[h * 128 + d]);
    float x2v = b2f(row[h * 128 + 64 + d]);
    u16* dst = q_r + ((long long)h * T_ + t) * HD_;
    dst[d] = f2b(x1v * c - x2v * s);
    dst[d + 64] = f2b(x1v * s + x2v * c);
  }
  {
    int item = tid;
    int kv = item >> 6, d = item & 63;
    float inv = expf(-cfac * (float)d);
    float ang = p * inv;
    float c = cosf(ang), s = sinf(ang);
    float x1v = b2f(row[NH_ * HD_ + kv * 128 + d]);
    float x2v = b2f(row[NH_ * HD_ + kv * 128 + 64 + d]);
    u16* dst = k_r + ((long long)kv * T_ + t) * HD_;
    dst[d] = f2b(x1v * c - x2v * s);
    dst[d + 64] = f2b(x1v * s + x2v * c);
  }
  #pragma unroll
  for (int it = 0; it < 2; ++it) {
    int item = it * 256 + tid;
    int kv = item >> 7, d = item & 127;
    v_r[((long long)kv * T_ + t) * HD_ + d] = row[(NH_ + NKV_) * HD_ + kv * 128 + d];
  }
}

__global__ __launch_bounds__(64) void softmax_k(u16* __restrict__ P) {
  int r = blockIdx.x;
  int h = r >> 10, i = r & 1023;
  u16* row = P + ((long long)h * T_ + i) * T_;
  int lane = threadIdx.x;
  int n = i + 1;
  float vals[16];
  float mx = -1e30f;
  #pragma unroll
  for (int it = 0; it < 16; ++it) {
    int j = it * 64 + lane;
    float s = (j < n) ? b2f(row[j]) : -1e30f;
    vals[it] = s;
    mx = fmaxf(mx, s);
  }
  #pragma unroll
  for (int o = 32; o; o >>= 1) mx = fmaxf(mx, __shfl_xor(mx, o));
  float sum = 0.f;
  #pragma unroll
  for (int it = 0; it < 16; ++it) {
    int j = it * 64 + lane;
    float e = (j < n) ? __expf(vals[it] - mx) : 0.f;
    vals[it] = e;
    sum += e;
  }
  #pragma unroll
  for (int o = 32; o; o >>= 1) sum += __shfl_xor(sum, o);
  float inv = 1.f / sum;
  #pragma unroll
  for (int it = 0; it < 16; ++it) {
    int j = it * 64 + lane;
    row[j] = f2b(vals[it] * inv);
  }
}

__global__ __launch_bounds__(64) void router_k(const float* __restrict__ h2,
                                               const float* __restrict__ wr,
                                               float* __restrict__ logits) {
  int b = blockIdx.x;
  int t = b >> 5, e = b & 31;
  const float* xr = h2 + (long long)t * H_;
  const float* wv = wr + (long long)e * H_;
  int lane = threadIdx.x;
  float s = 0.f;
  #pragma unroll
  for (int it = 0; it < 8; ++it) {
    int h = it * 256 + lane * 4;
    float4 a = *(const float4*)(xr + h);
    float4 w4 = *(const float4*)(wv + h);
    s += a.x * w4.x + a.y * w4.y + a.z * w4.z + a.w * w4.w;
  }
  #pragma unroll
  for (int o = 32; o; o >>= 1) s += __shfl_xor(s, o);
  if (lane == 0) logits[b] = s;
}

__global__ __launch_bounds__(256) void topk_k(const float* __restrict__ logits,
                                              int* __restrict__ topi,
                                              float* __restrict__ topw) {
  int t = blockIdx.x * 256 + threadIdx.x;
  if (t >= T_) return;
  float l[E_];
  #pragma unroll
  for (int e = 0; e < E_; ++e) l[e] = logits[t * E_ + e];
  int sel[TOPK_];
  float sv[TOPK_];
  unsigned used = 0;
  for (int j = 0; j < TOPK_; ++j) {
    float best = -1e30f;
    int bi = 0;
    for (int e = 0; e < E_; ++e) {
      if (used & (1u << e)) continue;
      if (l[e] > best) { best = l[e]; bi = e; }
    }
    used |= 1u << bi;
    sel[j] = bi;
    sv[j] = best;
  }
  float mx = sv[0];
  float s = 0.f;
  #pragma unroll
  for (int j = 0; j < TOPK_; ++j) { sv[j] = __expf(sv[j] - mx); s += sv[j]; }
  float inv = 1.f / s;
  #pragma unroll
  for (int j = 0; j < TOPK_; ++j) {
    topi[t * TOPK_ + j] = sel[j];
    topw[t * TOPK_ + j] = sv[j] * inv;
  }
}

__global__ __launch_bounds__(256) void hist_k(const int* __restrict__ topi, int* __restrict__ cnt) {
  int idx = blockIdx.x * 256 + threadIdx.x;
  if (idx < T_ * TOPK_) atomicAdd(&cnt[topi[idx]], 1);
}

__global__ __launch_bounds__(64) void scan_k(const int* __restrict__ cnt,
                                             int* __restrict__ eoff,
                                             int* __restrict__ cursor) {
  if (threadIdx.x == 0) {
    int s = 0;
    for (int e = 0; e < E_; ++e) { eoff[e] = s; cursor[e] = s; s += cnt[e]; }
    eoff[E_] = s;
  }
}

__global__ __launch_bounds__(256) void scatter_k(const int* __restrict__ topi,
                                                 const float* __restrict__ topw,
                                                 int* __restrict__ cursor,
                                                 int* __restrict__ slots,
                                                 float* __restrict__ slotw) {
  int idx = blockIdx.x * 256 + threadIdx.x;
  if (idx >= T_ * TOPK_) return;
  int e = topi[idx];
  int pos = atomicAdd(&cursor[e], 1);
  slots[pos] = idx >> 2;
  slotw[pos] = topw[idx];
}

__global__ __launch_bounds__(256) void silumul_f_k(const float* __restrict__ g,
                                                   const float* __restrict__ u,
                                                   u16* __restrict__ a) {
  long long idx = ((long long)blockIdx.x * 256 + threadIdx.x) * 8;
  float4 g0 = *(const float4*)(g + idx);
  float4 g1 = *(const float4*)(g + idx + 4);
  float4 u0 = *(const float4*)(u + idx);
  float4 u1 = *(const float4*)(u + idx + 4);
  float gv[8] = {g0.x, g0.y, g0.z, g0.w, g1.x, g1.y, g1.z, g1.w};
  float uv[8] = {u0.x, u0.y, u0.z, u0.w, u1.x, u1.y, u1.z, u1.w};
  u16x8 o;
  #pragma unroll
  for (int q = 0; q < 8; ++q) {
    float x = gv[q];
    float sl = x / (1.f + __expf(-x));
    o[q] = f2b(sl * uv[q]);
  }
  *(u16x8*)(a + idx) = o;
}

__global__ __launch_bounds__(256) void sharedact_k(const u16* __restrict__ gu,
                                                   u16* __restrict__ act) {
  long long idx = ((long long)blockIdx.x * 256 + threadIdx.x) * 8;
  long long t = idx >> 10;
  int i = (int)(idx & 1023);
  const u16* row = gu + t * (2 * I_);
  u16x8 g = *(const u16x8*)(row + i);
  u16x8 u = *(const u16x8*)(row + I_ + i);
  u16x8 o;
  #pragma unroll
  for (int q = 0; q < 8; ++q) {
    float x = b2f(g[q]);
    float y = b2f(u[q]);
    float sl = x / (1.f + __expf(-x));
    o[q] = f2b(sl * y);
  }
  *(u16x8*)(act + t * I_ + i) = o;
}

// ---------------------------------------------------------------------------
extern "C" void kernel_launch(void* const* d_in, const int* in_sizes, int n_in,
                              void* d_out, int out_size, void* d_ws, size_t ws_size,
                              hipStream_t stream) {
  const float* x        = (const float*)d_in[0];
  const int* positions  = (const int*)d_in[1];
  const float* w_rms1   = (const float*)d_in[2];
  const float* w_rms2   = (const float*)d_in[3];
  const float* w_qkv    = (const float*)d_in[4];
  const float* w_o      = (const float*)d_in[5];
  const float* w_router = (const float*)d_in[6];
  const float* w1       = (const float*)d_in[7];
  const float* w3       = (const float*)d_in[8];
  const float* w2       = (const float*)d_in[9];
  const float* ws_gu    = (const float*)d_in[10];
  const float* ws_dn    = (const float*)d_in[11];
  float* out = (float*)d_out;

  char* ws = (char*)d_ws;
  size_t off = 0;
  auto alloc = [&](size_t bytes) {
    size_t o = off;
    off = (off + bytes + 255) & ~(size_t)255;
    return (void*)(ws + o);
  };
  u16*  h1b     = (u16*)alloc((size_t)T_ * H_ * 2);
  u16*  qkvb    = (u16*)alloc((size_t)T_ * QKVN_ * 2);
  u16*  q_r     = (u16*)alloc((size_t)NH_ * T_ * HD_ * 2);
  u16*  k_r     = (u16*)alloc((size_t)NKV_ * T_ * HD_ * 2);
  u16*  v_r     = (u16*)alloc((size_t)NKV_ * T_ * HD_ * 2);
  u16*  scoresP = (u16*)alloc((size_t)NH_ * T_ * T_ * 2);   // reused as g/u f32
  u16*  o_attn  = (u16*)alloc((size_t)T_ * H_ * 2);
  float* x1     = (float*)alloc((size_t)T_ * H_ * 4);
  float* h2f    = (float*)alloc((size_t)T_ * H_ * 4);
  u16*  h2b     = (u16*)alloc((size_t)T_ * H_ * 2);
  u16*  gub     = (u16*)alloc((size_t)T_ * 2 * I_ * 2);
  u16*  actsh   = (u16*)alloc((size_t)T_ * I_ * 2);
  float* logits = (float*)alloc((size_t)T_ * E_ * 4);
  int*  topi    = (int*)alloc((size_t)T_ * TOPK_ * 4);
  float* topw   = (float*)alloc((size_t)T_ * TOPK_ * 4);
  int*  cnt     = (int*)alloc(E_ * 4);
  int*  eoffp   = (int*)alloc((E_ + 1) * 4);
  int*  cursor  = (int*)alloc(E_ * 4);
  int*  slots   = (int*)alloc((size_t)T_ * TOPK_ * 4);
  float* slotw  = (float*)alloc((size_t)T_ * TOPK_ * 4);
  u16*  a_g     = (u16*)alloc((size_t)T_ * TOPK_ * I_ * 2);
  float* routed = (float*)alloc((size_t)T_ * H_ * 4);

  float* g_f32 = (float*)scoresP;
  float* u_f32 = g_f32 + (size_t)T_ * TOPK_ * I_;

  hipMemsetAsync(routed, 0, (size_t)T_ * H_ * 4, stream);
  hipMemsetAsync(cnt, 0, E_ * 4, stream);

  // 1. h = rmsnorm(x, w_rms1)
  rmsnorm_k<<<T_, 256, 0, stream>>>(x, w_rms1, h1b, nullptr);

  // 2. qkv = h @ w_qkv.T
  gemm_k<float, true, false, false, 0><<<dim3(8, 24, 1), 256, 0, stream>>>(
      h1b, w_qkv, nullptr, qkvb, nullptr, nullptr, nullptr, nullptr,
      T_, QKVN_, H_, H_, H_, QKVN_, 1.f, 0, 1, 0, nullptr, nullptr, nullptr, 0, 0, 0, 1);

  // 3. RoPE + unpack
  rope_k<<<T_, 256, 0, stream>>>(qkvb, positions, q_r, k_r, v_r);

  // 4. scores = scale * q @ k^T per head (causal block-skip)
  gemm_k<u16, true, false, false, 1><<<dim3(8, 8, NH_), 256, 0, stream>>>(
      q_r, k_r, nullptr, scoresP, nullptr, nullptr, nullptr, nullptr,
      T_, T_, HD_, HD_, HD_, T_, SCALE_, 1, 1, 0, nullptr, nullptr, nullptr,
      (long long)T_ * HD_, (long long)T_ * HD_, (long long)T_ * T_, NH_ / NKV_);

  // 5. masked softmax rows
  softmax_k<<<NH_ * T_, 64, 0, stream>>>(scoresP);

  // 6. o = P @ V per head (A-causal K bound)
  gemm_k<u16, false, false, false, 0><<<dim3(8, 1, NH_), 256, 0, stream>>>(
      scoresP, v_r, nullptr, o_attn, nullptr, nullptr, nullptr, nullptr,
      T_, HD_, T_, T_, HD_, H_, 1.f, 2, 1, 0, nullptr, nullptr, nullptr,
      (long long)T_ * T_, (long long)T_ * HD_, (long long)HD_, NH_ / NKV_);

  // 7. x1 = x + o @ w_o.T
  gemm_k<float, true, false, false, 2><<<dim3(8, 16, 1), 256, 0, stream>>>(
      o_attn, w_o, nullptr, nullptr, nullptr, x1, x, nullptr,
      T_, H_, H_, H_, H_, H_, 1.f, 0, 1, 0, nullptr, nullptr, nullptr, 0, 0, 0, 1);

  // scoresP dead -> zero g/u accumulators
  hipMemsetAsync(g_f32, 0, (size_t)T_ * TOPK_ * I_ * 8, stream);

  // 8. h2 = rmsnorm(x1, w_rms2)
  rmsnorm_k<<<T_, 256, 0, stream>>>(x1, w_rms2, h2b, h2f);

  // 9. router
  router_k<<<T_ * E_, 64, 0, stream>>>(h2f, w_router, logits);
  topk_k<<<4, 256, 0, stream>>>(logits, topi, topw);
  hist_k<<<16, 256, 0, stream>>>(topi, cnt);
  scan_k<<<1, 64, 0, stream>>>(cnt, eoffp, cursor);
  scatter_k<<<16, 256, 0, stream>>>(topi, topw, cursor, slots, slotw);

  // 10. fused grouped up: g += X_e @ w1[e] (x<8), u += X_e @ w3[e] (x>=8)
  moe_gemm_k<0, true><<<dim3(16, E_ * 8, 4), 512, 0, stream>>>(
      h2b, w1, w3, g_f32, u_f32,
      I_, H_, I_, H_ / 4, eoffp, slots, nullptr, (long long)H_ * I_);
  silumul_f_k<<<(T_ * TOPK_ * I_) / (256 * 8), 256, 0, stream>>>(g_f32, u_f32, a_g);

  // 11. grouped down: routed[t] += w * (a_e @ w2[e])
  moe_gemm_k<1, false><<<dim3(16, E_ * 8, 4), 512, 0, stream>>>(
      a_g, w2, nullptr, routed, nullptr,
      H_, I_, H_, I_ / 4, eoffp, slots, slotw, (long long)I_ * H_);

  // 12. shared expert
  gemm_k<float, true, false, false, 0><<<dim3(8, 16, 1), 256, 0, stream>>>(
      h2b, ws_gu, nullptr, gub, nullptr, nullptr, nullptr, nullptr,
      T_, 2 * I_, H_, H_, H_, 2 * I_, 1.f, 0, 1, 0, nullptr, nullptr, nullptr, 0, 0, 0, 1);
  sharedact_k<<<(T_ * I_) / (256 * 8), 256, 0, stream>>>(gub, actsh);

  // 13. out = f32(x1 + routed + act @ ws_down.T)
  gemm_k<float, true, false, false, 4><<<dim3(8, 16, 1), 256, 0, stream>>>(
      actsh, ws_dn, nullptr, nullptr, nullptr, out, x1, routed,
      T_, H_, I_, I_, I_, H_, 1.f, 0, 1, 0, nullptr, nullptr, nullptr, 0, 0, 0, 1);
}

// Round 7
// 607.454 us; speedup vs baseline: 6.2450x; 1.0519x over previous
//
#include <hip/hip_runtime.h>
#include <hip/hip_bf16.h>
#include <math.h>
#include <stdint.h>

#define T_ 1024
#define H_ 2048
#define NH_ 16
#define NKV_ 4
#define HD_ 128
#define E_ 32
#define TOPK_ 4
#define I_ 1024
#define QKVN_ 3072
#define EPS_ 1e-6f
#define THETA_ 600000.0f
#define SCALE_ 0.08838834764831845f

typedef unsigned short u16;
typedef u16 u16x4 __attribute__((ext_vector_type(4)));
typedef u16 u16x8 __attribute__((ext_vector_type(8)));
typedef __bf16 bf16x8 __attribute__((ext_vector_type(8)));
typedef float f32x4 __attribute__((ext_vector_type(4)));

__device__ __forceinline__ u16 f2b(float f) {
  unsigned u = __builtin_bit_cast(unsigned, f);
  u += 0x7FFFu + ((u >> 16) & 1u);
  return (u16)(u >> 16);
}
__device__ __forceinline__ float b2f(u16 x) {
  unsigned u = ((unsigned)x) << 16;
  return __builtin_bit_cast(float, u);
}
__device__ __forceinline__ int swz8(int r) { return ((r ^ (r >> 3)) & 7) << 3; }

__device__ __forceinline__ void gload16(const void* g, void* l) {
  __builtin_amdgcn_global_load_lds(
      reinterpret_cast<const __attribute__((address_space(1))) unsigned int*>(
          reinterpret_cast<uintptr_t>(g)),
      reinterpret_cast<__attribute__((address_space(3))) unsigned int*>(
          reinterpret_cast<uintptr_t>(l)),
      16, 0, 0);
}

// ---------------------------------------------------------------------------
// MoE grouped GEMM, M64 x N128 x BK32, 512 threads (8 waves, 2m x 4n),
// 2-buffer LDS (24 KB) -> 4 blocks/CU = 32 waves/CU.
// A: bf16, DMA'd to LDS (waves 0-3, swizzled source).
// B: f32 [k][n]; reg-staged (8 wave-coalesced dwords/thread), converted to
// bf16 ONCE at staging, stored transposed [n][k] in LDS with 2-bit XOR
// swizzle -> all fragment loads are ds_read_b128, ~2-way (free).
// grid: x = nstripe, y = e*8 + mb, z = split-K (2).
// EPI 0: fused up (x<8 -> w1/O1, x>=8 -> w3/O2), atomicAdd at slot row.
// EPI 1: down, atomicAdd slotw*acc into O1[token].
// ---------------------------------------------------------------------------
template<int EPI, bool GATHER>
__global__ __launch_bounds__(512, 8) void moe_gemm_k(
    const u16* __restrict__ A, const float* __restrict__ B, const float* __restrict__ B2,
    float* __restrict__ O1, float* __restrict__ O2,
    int NW, int lda, int ldb, int kchunk,
    const int* __restrict__ eoff, const int* __restrict__ slots,
    const float* __restrict__ slotw, long long sBz)
{
  __shared__ u16 As[2][64 * 32];     // 4 KB per buffer
  __shared__ u16 Bs[2][128 * 32];    // 8 KB per buffer

  const int e = blockIdx.y >> 3;
  const int mb = blockIdx.y & 7;
  const int goff = eoff[e];
  const int Mloc = eoff[e + 1] - goff;
  const int m0 = mb * 64;
  if (m0 >= Mloc) return;

  const int xx = blockIdx.x;
  const float* Bp;
  float* Op;
  int n0;
  if constexpr (EPI == 0) {
    int wsel = xx >> 3;
    n0 = (xx & 7) * 128;
    Bp = (wsel ? B2 : B) + (long long)e * sBz;
    Op = wsel ? O2 : O1;
  } else {
    n0 = xx * 128;
    Bp = B + (long long)e * sBz;
    Op = O1;
  }
  const int k0base = blockIdx.z * kchunk;
  const u16* Ae = GATHER ? A : (A + (long long)goff * lda);

  const int tid = threadIdx.x;
  const int lane = tid & 63;
  const int wv = tid >> 6;           // 0..7
  const int wm = wv >> 2, wn = wv & 3;

  // A staging base (waves 0-3 only): 16 rows x 32k per wave-inst (1 KB)
  const u16* Abase = nullptr;
  if (wv < 4) {
    int r = wv * 16 + (lane >> 2);
    int rr = m0 + r;
    if (rr > Mloc - 1) rr = Mloc - 1;
    long long grow = GATHER ? (long long)slots[goff + rr] : (long long)rr;
    Abase = Ae + grow * (long long)lda + (((lane & 3) ^ (r & 3)) << 3);
  }

  // B reg staging: thread covers n = tid&127, k-slot (tid>>7)*8 .. +7
  const int bn = tid & 127;
  const int bkb = (tid >> 7) << 3;
  const float* Bbase = Bp + (long long)bkb * ldb + n0 + bn;
  const int bws = bn * 32 + (bkb ^ ((((bn ^ (bn >> 3)) & 3)) << 3));

  float br[8];
  auto loadB = [&](int k0) {
    const float* p = Bbase + (long long)k0 * ldb;
    #pragma unroll
    for (int j = 0; j < 8; ++j) br[j] = p[(long long)j * ldb];
  };
  auto writeB = [&](int bf) {
    u16x8 o;
    #pragma unroll
    for (int j = 0; j < 8; ++j) o[j] = f2b(br[j]);
    *(u16x8*)(&Bs[bf][bws]) = o;
  };
  auto stageA = [&](int bf, int k0) {
    if (wv < 4) gload16(Abase + k0, &As[bf][wv * 512]);
  };

  f32x4 acc[2][2];
  #pragma unroll
  for (int m = 0; m < 2; ++m)
    #pragma unroll
    for (int n = 0; n < 2; ++n)
      acc[m][n] = f32x4{0.f, 0.f, 0.f, 0.f};

  const int kg = lane >> 4;          // k-group 0..3
  const int cr = lane & 15;

  // frag offsets (precomputed)
  int aoff[2], boff[2];
  #pragma unroll
  for (int m = 0; m < 2; ++m) {
    int r = wm * 32 + m * 16 + cr;
    aoff[m] = r * 32 + ((kg ^ (r & 3)) << 3);
  }
  #pragma unroll
  for (int n = 0; n < 2; ++n) {
    int c = wn * 32 + n * 16 + cr;
    boff[n] = c * 32 + ((kg ^ ((c ^ (c >> 3)) & 3)) << 3);
  }

  // prologue
  loadB(k0base);
  stageA(0, k0base);
  writeB(0);
  __syncthreads();

  int buf = 0;
  for (int ks = 0; ks < kchunk; ks += 32) {
    bool more = (ks + 32) < kchunk;
    if (more) { loadB(k0base + ks + 32); stageA(buf ^ 1, k0base + ks + 32); }
    const u16* Ap = &As[buf][0];
    const u16* Bq = &Bs[buf][0];
    bf16x8 af[2], bfr[2];
    #pragma unroll
    for (int m = 0; m < 2; ++m)
      af[m] = __builtin_bit_cast(bf16x8, *(const u16x8*)(Ap + aoff[m]));
    #pragma unroll
    for (int n = 0; n < 2; ++n)
      bfr[n] = __builtin_bit_cast(bf16x8, *(const u16x8*)(Bq + boff[n]));
    #pragma unroll
    for (int m = 0; m < 2; ++m)
      #pragma unroll
      for (int n = 0; n < 2; ++n)
        acc[m][n] = __builtin_amdgcn_mfma_f32_16x16x32_bf16(af[m], bfr[n], acc[m][n], 0, 0, 0);
    if (more) writeB(buf ^ 1);
    __syncthreads();
    buf ^= 1;
  }

  const int rq = lane >> 4;
  #pragma unroll
  for (int m = 0; m < 2; ++m) {
    #pragma unroll
    for (int j = 0; j < 4; ++j) {
      int row = m0 + wm * 32 + m * 16 + rq * 4 + j;
      if (row >= Mloc) continue;
      if constexpr (EPI == 0) {
        float* dst = Op + (long long)(goff + row) * NW;
        #pragma unroll
        for (int n = 0; n < 2; ++n) {
          int col = n0 + wn * 32 + n * 16 + cr;
          atomicAdd(dst + col, acc[m][n][j]);
        }
      } else {
        int tok = slots[goff + row];
        float wgt = slotw[goff + row];
        float* dst = Op + (long long)tok * NW;
        #pragma unroll
        for (int n = 0; n < 2; ++n) {
          int col = n0 + wn * 32 + n * 16 + cr;
          atomicAdd(dst + col, wgt * acc[m][n][j]);
        }
      }
    }
  }
}

// ---------------------------------------------------------------------------
// Generic 128x128 (BK=64) GEMM (non-MoE uses).
// ---------------------------------------------------------------------------
template<typename TB, bool BTL, bool GROUPED, bool GATHER, int EPI>
__global__ __launch_bounds__(256) void gemm_k(
    const u16* __restrict__ A, const TB* __restrict__ B, const TB* __restrict__ B2,
    u16* __restrict__ Cb, u16* __restrict__ Cb2, float* __restrict__ Cf,
    const float* __restrict__ res1, const float* __restrict__ res2,
    int M, int N, int K, int lda, int ldb, int ldc,
    float alpha, int causal, int mbmax, int yhalf,
    const int* __restrict__ eoff, const int* __restrict__ slots,
    const float* __restrict__ slotw,
    long long sAz, long long sBz, long long sCz, int bdivz)
{
  __shared__ u16 As[2][8192];
  __shared__ u16 Bs[2][8192];

  int m0, n0, Mloc, goff = 0;
  const u16* Ae = A;
  const TB* Be = B;
  u16* Cw = Cb;
  if (GROUPED) {
    int e = blockIdx.x / mbmax;
    int mb = blockIdx.x - e * mbmax;
    goff = eoff[e];
    Mloc = eoff[e + 1] - goff;
    m0 = mb * 128;
    if (m0 >= Mloc) return;
    int by = blockIdx.y;
    if (yhalf && by >= yhalf) {
      n0 = (by - yhalf) * 128;
      Be = B2 + (long long)e * sBz;
      Cw = Cb2;
    } else {
      n0 = by * 128;
      Be = B + (long long)e * sBz;
    }
    if (!GATHER) Ae = A + (long long)goff * lda;
  } else {
    m0 = blockIdx.x * 128;
    n0 = blockIdx.y * 128;
    Mloc = M;
    long long z = blockIdx.z;
    Ae = A + z * sAz;
    Be = B + (long long)(z / bdivz) * sBz;
    if (Cb) Cw = Cb + z * sCz;
    if (causal == 1 && n0 > m0 + 127) return;
  }

  const int tid = threadIdx.x;
  const int lane = tid & 63;
  const int wv = tid >> 6;
  const int wr = wv >> 1, wc = wv & 1;

  int kend = K;
  if (causal == 2) { int ke = m0 + 128; if (ke < kend) kend = ke; }

  f32x4 acc[4][4];
  #pragma unroll
  for (int i = 0; i < 4; ++i)
    #pragma unroll
    for (int j = 0; j < 4; ++j)
      acc[i][j] = f32x4{0.f, 0.f, 0.f, 0.f};

  auto stageA = [&](int bf, int k0) {
    #pragma unroll
    for (int it = 0; it < 4; ++it) {
      int r = it * 32 + (tid >> 3);
      int kk = (tid & 7) * 8;
      int rr = m0 + r;
      if (rr > Mloc - 1) rr = Mloc - 1;
      long long row = GATHER ? (long long)slots[goff + rr] : (long long)rr;
      const u16* src = Ae + row * (long long)lda + k0 + (kk ^ swz8(r));
      gload16(src, &As[bf][it * 2048 + (tid & ~63) * 8]);
    }
  };

  float4 bregT[8];
  float brKN[32];
  u16x8 bvKN[4];

  auto loadB = [&](int bf, int k0) {
    if constexpr (BTL) {
      if constexpr (sizeof(TB) == 4) {
        const float* Bf = (const float*)Be;
        #pragma unroll
        for (int it = 0; it < 8; ++it) {
          int idx = it * 1024 + tid * 4;
          int n = idx >> 6, kk = idx & 63;
          bregT[it] = *(const float4*)(Bf + (long long)(n0 + n) * ldb + k0 + kk);
        }
      } else {
        const u16* Bb = (const u16*)Be;
        #pragma unroll
        for (int it = 0; it < 4; ++it) {
          int r = it * 32 + (tid >> 3);
          int kk = (tid & 7) * 8;
          const u16* src = Bb + (long long)(n0 + r) * ldb + k0 + (kk ^ swz8(r));
          gload16(src, &Bs[bf][it * 2048 + (tid & ~63) * 8]);
        }
      }
    } else {
      if constexpr (sizeof(TB) == 4) {
        const float* Bf = (const float*)Be;
        int n = (tid & 63) + ((tid >> 7) << 6);
        int ks = ((tid >> 6) & 1) * 32;
        const float* bp = Bf + (long long)(k0 + ks) * ldb + n0 + n;
        #pragma unroll
        for (int j = 0; j < 32; ++j) brKN[j] = bp[(long long)j * ldb];
      } else {
        const u16* Bb = (const u16*)Be;
        int nb = (tid & 15) * 8;
        int ks = (tid >> 4) * 4;
        #pragma unroll
        for (int i = 0; i < 4; ++i)
          bvKN[i] = *(const u16x8*)(Bb + (long long)(k0 + ks + i) * ldb + n0 + nb);
      }
    }
  };

  auto writeB = [&](int bf) {
    if constexpr (BTL) {
      if constexpr (sizeof(TB) == 4) {
        #pragma unroll
        for (int it = 0; it < 8; ++it) {
          int idx = it * 1024 + tid * 4;
          int n = idx >> 6, kk = idx & 63;
          float4 f = bregT[it];
          u16x4 o = u16x4{f2b(f.x), f2b(f.y), f2b(f.z), f2b(f.w)};
          *(u16x4*)(&Bs[bf][n * 64 + (kk ^ swz8(n))]) = o;
        }
      }
    } else {
      if constexpr (sizeof(TB) == 4) {
        int n = (tid & 63) + ((tid >> 7) << 6);
        int ks = ((tid >> 6) & 1) * 32;
        #pragma unroll
        for (int p = 0; p < 4; ++p) {
          u16x8 o;
          #pragma unroll
          for (int q = 0; q < 8; ++q) o[q] = f2b(brKN[p * 8 + q]);
          *(u16x8*)(&Bs[bf][n * 64 + ((ks + p * 8) ^ swz8(n))]) = o;
        }
      } else {
        int nb = (tid & 15) * 8;
        int ks = (tid >> 4) * 4;
        #pragma unroll
        for (int q = 0; q < 8; ++q) {
          int n = nb + q;
          u16x4 o = u16x4{bvKN[0][q], bvKN[1][q], bvKN[2][q], bvKN[3][q]};
          *(u16x4*)(&Bs[bf][n * 64 + (ks ^ swz8(n))]) = o;
        }
      }
    }
  };

  const int ar = (wr << 6) + (lane & 15);
  const int bc = (wc << 6) + (lane & 15);
  int aoff[4], asw[4], boff[4], bsw[4];
  #pragma unroll
  for (int m = 0; m < 4; ++m) {
    int r = ar + m * 16; aoff[m] = r * 64; asw[m] = swz8(r);
    int rb = bc + m * 16; boff[m] = rb * 64; bsw[m] = swz8(rb);
  }

  stageA(0, 0);
  loadB(0, 0);
  writeB(0);
  __syncthreads();

  int buf = 0;
  for (int k0 = 0; k0 < kend; k0 += 64) {
    int nk = k0 + 64;
    bool more = nk < kend;
    if (more) { stageA(buf ^ 1, nk); loadB(buf ^ 1, nk); }
    const u16* Ap = &As[buf][0];
    const u16* Bp = &Bs[buf][0];
    #pragma unroll
    for (int kk = 0; kk < 64; kk += 32) {
      int kb = kk + ((lane >> 4) << 3);
      bf16x8 af[4], bfr[4];
      #pragma unroll
      for (int m = 0; m < 4; ++m)
        af[m] = __builtin_bit_cast(bf16x8, *(const u16x8*)(Ap + aoff[m] + (kb ^ asw[m])));
      #pragma unroll
      for (int n = 0; n < 4; ++n)
        bfr[n] = __builtin_bit_cast(bf16x8, *(const u16x8*)(Bp + boff[n] + (kb ^ bsw[n])));
      #pragma unroll
      for (int m = 0; m < 4; ++m)
        #pragma unroll
        for (int n = 0; n < 4; ++n)
          acc[m][n] = __builtin_amdgcn_mfma_f32_16x16x32_bf16(af[m], bfr[n], acc[m][n], 0, 0, 0);
    }
    if (more) writeB(buf ^ 1);
    __syncthreads();
    buf ^= 1;
  }

  const int cr = lane & 15, rq = lane >> 4;
  #pragma unroll
  for (int m = 0; m < 4; ++m) {
    #pragma unroll
    for (int j = 0; j < 4; ++j) {
      int row = m0 + (wr << 6) + m * 16 + rq * 4 + j;
      if (row >= Mloc) continue;
      #pragma unroll
      for (int n = 0; n < 4; ++n) {
        int col = n0 + (wc << 6) + n * 16 + cr;
        float v = acc[m][n][j];
        long long o = (long long)(goff + row) * ldc + col;
        if constexpr (EPI == 0) {
          Cw[o] = f2b(v);
        } else if constexpr (EPI == 1) {
          Cw[o] = f2b(v * alpha);
        } else if constexpr (EPI == 2) {
          Cf[o] = res1[o] + v;
        } else if constexpr (EPI == 3) {
          int tok = slots[goff + row];
          float wgt = slotw[goff + row];
          atomicAdd(&Cf[(long long)tok * ldc + col], wgt * v);
        } else {
          Cf[o] = res1[o] + res2[o] + v;
        }
      }
    }
  }
}

// ---------------------------------------------------------------------------
__global__ __launch_bounds__(256) void rmsnorm_k(const float* __restrict__ x,
                                                 const float* __restrict__ w,
                                                 u16* __restrict__ outb,
                                                 float* __restrict__ outf) {
  int t = blockIdx.x;
  int tid = threadIdx.x;
  const float* xr = x + (long long)t * H_;
  float4 a = *(const float4*)(xr + tid * 8);
  float4 b = *(const float4*)(xr + tid * 8 + 4);
  float ss = a.x * a.x + a.y * a.y + a.z * a.z + a.w * a.w +
             b.x * b.x + b.y * b.y + b.z * b.z + b.w * b.w;
  #pragma unroll
  for (int o = 32; o; o >>= 1) ss += __shfl_down(ss, o);
  __shared__ float red[4];
  if ((tid & 63) == 0) red[tid >> 6] = ss;
  __syncthreads();
  float sc = rsqrtf((red[0] + red[1] + red[2] + red[3]) * (1.0f / H_) + EPS_);
  float vo[8] = {a.x, a.y, a.z, a.w, b.x, b.y, b.z, b.w};
  const float* wr = w + tid * 8;
  u16x8 ob;
  #pragma unroll
  for (int q = 0; q < 8; ++q) {
    float val = vo[q] * sc * wr[q];
    ob[q] = f2b(val);
    if (outf) outf[(long long)t * H_ + tid * 8 + q] = val;
  }
  *(u16x8*)(outb + (long long)t * H_ + tid * 8) = ob;
}

__global__ __launch_bounds__(256) void rope_k(const u16* __restrict__ qkv,
                                              const int* __restrict__ pos,
                                              u16* __restrict__ q_r,
                                              u16* __restrict__ k_r,
                                              u16* __restrict__ v_r) {
  int t = blockIdx.x;
  int tid = threadIdx.x;
  float p = (float)pos[t];
  const u16* row = qkv + (long long)t * QKVN_;
  const float cfac = logf(THETA_) * (1.0f / 64.0f);
  #pragma unroll
  for (int it = 0; it < 4; ++it) {
    int item = it * 256 + tid;
    int h = item >> 6, d = item & 63;
    float inv = expf(-cfac * (float)d);
    float ang = p * inv;
    float c = cosf(ang), s = sinf(ang);
    float x1v = b2f(row[h * 128 + d]);
    float x2v = b2f(row[h * 128 + 64 + d]);
    u16* dst = q_r + ((long long)h * T_ + t) * HD_;
    dst[d] = f2b(x1v * c - x2v * s);
    dst[d + 64] = f2b(x1v * s + x2v * c);
  }
  {
    int item = tid;
    int kv = item >> 6, d = item & 63;
    float inv = expf(-cfac * (float)d);
    float ang = p * inv;
    float c = cosf(ang), s = sinf(ang);
    float x1v = b2f(row[NH_ * HD_ + kv * 128 + d]);
    float x2v = b2f(row[NH_ * HD_ + kv * 128 + 64 + d]);
    u16* dst = k_r + ((long long)kv * T_ + t) * HD_;
    dst[d] = f2b(x1v * c - x2v * s);
    dst[d + 64] = f2b(x1v * s + x2v * c);
  }
  #pragma unroll
  for (int it = 0; it < 2; ++it) {
    int item = it * 256 + tid;
    int kv = item >> 7, d = item & 127;
    v_r[((long long)kv * T_ + t) * HD_ + d] = row[(NH_ + NKV_) * HD_ + kv * 128 + d];
  }
}

__global__ __launch_bounds__(64) void softmax_k(u16* __restrict__ P) {
  int r = blockIdx.x;
  int h = r >> 10, i = r & 1023;
  u16* row = P + ((long long)h * T_ + i) * T_;
  int lane = threadIdx.x;
  int n = i + 1;
  float vals[16];
  float mx = -1e30f;
  #pragma unroll
  for (int it = 0; it < 16; ++it) {
    int j = it * 64 + lane;
    float s = (j < n) ? b2f(row[j]) : -1e30f;
    vals[it] = s;
    mx = fmaxf(mx, s);
  }
  #pragma unroll
  for (int o = 32; o; o >>= 1) mx = fmaxf(mx, __shfl_xor(mx, o));
  float sum = 0.f;
  #pragma unroll
  for (int it = 0; it < 16; ++it) {
    int j = it * 64 + lane;
    float e = (j < n) ? __expf(vals[it] - mx) : 0.f;
    vals[it] = e;
    sum += e;
  }
  #pragma unroll
  for (int o = 32; o; o >>= 1) sum += __shfl_xor(sum, o);
  float inv = 1.f / sum;
  #pragma unroll
  for (int it = 0; it < 16; ++it) {
    int j = it * 64 + lane;
    row[j] = f2b(vals[it] * inv);
  }
}

__global__ __launch_bounds__(64) void router_k(const float* __restrict__ h2,
                                               const float* __restrict__ wr,
                                               float* __restrict__ logits) {
  int b = blockIdx.x;
  int t = b >> 5, e = b & 31;
  const float* xr = h2 + (long long)t * H_;
  const float* wv = wr + (long long)e * H_;
  int lane = threadIdx.x;
  float s = 0.f;
  #pragma unroll
  for (int it = 0; it < 8; ++it) {
    int h = it * 256 + lane * 4;
    float4 a = *(const float4*)(xr + h);
    float4 w4 = *(const float4*)(wv + h);
    s += a.x * w4.x + a.y * w4.y + a.z * w4.z + a.w * w4.w;
  }
  #pragma unroll
  for (int o = 32; o; o >>= 1) s += __shfl_xor(s, o);
  if (lane == 0) logits[b] = s;
}

__global__ __launch_bounds__(256) void topk_k(const float* __restrict__ logits,
                                              int* __restrict__ topi,
                                              float* __restrict__ topw) {
  int t = blockIdx.x * 256 + threadIdx.x;
  if (t >= T_) return;
  float l[E_];
  #pragma unroll
  for (int e = 0; e < E_; ++e) l[e] = logits[t * E_ + e];
  int sel[TOPK_];
  float sv[TOPK_];
  unsigned used = 0;
  for (int j = 0; j < TOPK_; ++j) {
    float best = -1e30f;
    int bi = 0;
    for (int e = 0; e < E_; ++e) {
      if (used & (1u << e)) continue;
      if (l[e] > best) { best = l[e]; bi = e; }
    }
    used |= 1u << bi;
    sel[j] = bi;
    sv[j] = best;
  }
  float mx = sv[0];
  float s = 0.f;
  #pragma unroll
  for (int j = 0; j < TOPK_; ++j) { sv[j] = __expf(sv[j] - mx); s += sv[j]; }
  float inv = 1.f / s;
  #pragma unroll
  for (int j = 0; j < TOPK_; ++j) {
    topi[t * TOPK_ + j] = sel[j];
    topw[t * TOPK_ + j] = sv[j] * inv;
  }
}

__global__ __launch_bounds__(256) void hist_k(const int* __restrict__ topi, int* __restrict__ cnt) {
  int idx = blockIdx.x * 256 + threadIdx.x;
  if (idx < T_ * TOPK_) atomicAdd(&cnt[topi[idx]], 1);
}

__global__ __launch_bounds__(64) void scan_k(const int* __restrict__ cnt,
                                             int* __restrict__ eoff,
                                             int* __restrict__ cursor) {
  if (threadIdx.x == 0) {
    int s = 0;
    for (int e = 0; e < E_; ++e) { eoff[e] = s; cursor[e] = s; s += cnt[e]; }
    eoff[E_] = s;
  }
}

__global__ __launch_bounds__(256) void scatter_k(const int* __restrict__ topi,
                                                 const float* __restrict__ topw,
                                                 int* __restrict__ cursor,
                                                 int* __restrict__ slots,
                                                 float* __restrict__ slotw) {
  int idx = blockIdx.x * 256 + threadIdx.x;
  if (idx >= T_ * TOPK_) return;
  int e = topi[idx];
  int pos = atomicAdd(&cursor[e], 1);
  slots[pos] = idx >> 2;
  slotw[pos] = topw[idx];
}

__global__ __launch_bounds__(256) void silumul_f_k(const float* __restrict__ g,
                                                   const float* __restrict__ u,
                                                   u16* __restrict__ a) {
  long long idx = ((long long)blockIdx.x * 256 + threadIdx.x) * 8;
  float4 g0 = *(const float4*)(g + idx);
  float4 g1 = *(const float4*)(g + idx + 4);
  float4 u0 = *(const float4*)(u + idx);
  float4 u1 = *(const float4*)(u + idx + 4);
  float gv[8] = {g0.x, g0.y, g0.z, g0.w, g1.x, g1.y, g1.z, g1.w};
  float uv[8] = {u0.x, u0.y, u0.z, u0.w, u1.x, u1.y, u1.z, u1.w};
  u16x8 o;
  #pragma unroll
  for (int q = 0; q < 8; ++q) {
    float x = gv[q];
    float sl = x / (1.f + __expf(-x));
    o[q] = f2b(sl * uv[q]);
  }
  *(u16x8*)(a + idx) = o;
}

__global__ __launch_bounds__(256) void sharedact_k(const u16* __restrict__ gu,
                                                   u16* __restrict__ act) {
  long long idx = ((long long)blockIdx.x * 256 + threadIdx.x) * 8;
  long long t = idx >> 10;
  int i = (int)(idx & 1023);
  const u16* row = gu + t * (2 * I_);
  u16x8 g = *(const u16x8*)(row + i);
  u16x8 u = *(const u16x8*)(row + I_ + i);
  u16x8 o;
  #pragma unroll
  for (int q = 0; q < 8; ++q) {
    float x = b2f(g[q]);
    float y = b2f(u[q]);
    float sl = x / (1.f + __expf(-x));
    o[q] = f2b(sl * y);
  }
  *(u16x8*)(act + t * I_ + i) = o;
}

// ---------------------------------------------------------------------------
extern "C" void kernel_launch(void* const* d_in, const int* in_sizes, int n_in,
                              void* d_out, int out_size, void* d_ws, size_t ws_size,
                              hipStream_t stream) {
  const float* x        = (const float*)d_in[0];
  const int* positions  = (const int*)d_in[1];
  const float* w_rms1   = (const float*)d_in[2];
  const float* w_rms2   = (const float*)d_in[3];
  const float* w_qkv    = (const float*)d_in[4];
  const float* w_o      = (const float*)d_in[5];
  const float* w_router = (const float*)d_in[6];
  const float* w1       = (const float*)d_in[7];
  const float* w3       = (const float*)d_in[8];
  const float* w2       = (const float*)d_in[9];
  const float* ws_gu    = (const float*)d_in[10];
  const float* ws_dn    = (const float*)d_in[11];
  float* out = (float*)d_out;

  char* ws = (char*)d_ws;
  size_t off = 0;
  auto alloc = [&](size_t bytes) {
    size_t o = off;
    off = (off + bytes + 255) & ~(size_t)255;
    return (void*)(ws + o);
  };
  u16*  h1b     = (u16*)alloc((size_t)T_ * H_ * 2);
  u16*  qkvb    = (u16*)alloc((size_t)T_ * QKVN_ * 2);
  u16*  q_r     = (u16*)alloc((size_t)NH_ * T_ * HD_ * 2);
  u16*  k_r     = (u16*)alloc((size_t)NKV_ * T_ * HD_ * 2);
  u16*  v_r     = (u16*)alloc((size_t)NKV_ * T_ * HD_ * 2);
  u16*  scoresP = (u16*)alloc((size_t)NH_ * T_ * T_ * 2);   // reused as g/u f32
  u16*  o_attn  = (u16*)alloc((size_t)T_ * H_ * 2);
  float* x1     = (float*)alloc((size_t)T_ * H_ * 4);
  float* h2f    = (float*)alloc((size_t)T_ * H_ * 4);
  u16*  h2b     = (u16*)alloc((size_t)T_ * H_ * 2);
  u16*  gub     = (u16*)alloc((size_t)T_ * 2 * I_ * 2);
  u16*  actsh   = (u16*)alloc((size_t)T_ * I_ * 2);
  float* logits = (float*)alloc((size_t)T_ * E_ * 4);
  int*  topi    = (int*)alloc((size_t)T_ * TOPK_ * 4);
  float* topw   = (float*)alloc((size_t)T_ * TOPK_ * 4);
  int*  cnt     = (int*)alloc(E_ * 4);
  int*  eoffp   = (int*)alloc((E_ + 1) * 4);
  int*  cursor  = (int*)alloc(E_ * 4);
  int*  slots   = (int*)alloc((size_t)T_ * TOPK_ * 4);
  float* slotw  = (float*)alloc((size_t)T_ * TOPK_ * 4);
  u16*  a_g     = (u16*)alloc((size_t)T_ * TOPK_ * I_ * 2);
  float* routed = (float*)alloc((size_t)T_ * H_ * 4);

  float* g_f32 = (float*)scoresP;
  float* u_f32 = g_f32 + (size_t)T_ * TOPK_ * I_;

  hipMemsetAsync(routed, 0, (size_t)T_ * H_ * 4, stream);
  hipMemsetAsync(cnt, 0, E_ * 4, stream);

  // 1. h = rmsnorm(x, w_rms1)
  rmsnorm_k<<<T_, 256, 0, stream>>>(x, w_rms1, h1b, nullptr);

  // 2. qkv = h @ w_qkv.T
  gemm_k<float, true, false, false, 0><<<dim3(8, 24, 1), 256, 0, stream>>>(
      h1b, w_qkv, nullptr, qkvb, nullptr, nullptr, nullptr, nullptr,
      T_, QKVN_, H_, H_, H_, QKVN_, 1.f, 0, 1, 0, nullptr, nullptr, nullptr, 0, 0, 0, 1);

  // 3. RoPE + unpack
  rope_k<<<T_, 256, 0, stream>>>(qkvb, positions, q_r, k_r, v_r);

  // 4. scores = scale * q @ k^T per head (causal block-skip)
  gemm_k<u16, true, false, false, 1><<<dim3(8, 8, NH_), 256, 0, stream>>>(
      q_r, k_r, nullptr, scoresP, nullptr, nullptr, nullptr, nullptr,
      T_, T_, HD_, HD_, HD_, T_, SCALE_, 1, 1, 0, nullptr, nullptr, nullptr,
      (long long)T_ * HD_, (long long)T_ * HD_, (long long)T_ * T_, NH_ / NKV_);

  // 5. masked softmax rows
  softmax_k<<<NH_ * T_, 64, 0, stream>>>(scoresP);

  // 6. o = P @ V per head (A-causal K bound)
  gemm_k<u16, false, false, false, 0><<<dim3(8, 1, NH_), 256, 0, stream>>>(
      scoresP, v_r, nullptr, o_attn, nullptr, nullptr, nullptr, nullptr,
      T_, HD_, T_, T_, HD_, H_, 1.f, 2, 1, 0, nullptr, nullptr, nullptr,
      (long long)T_ * T_, (long long)T_ * HD_, (long long)HD_, NH_ / NKV_);

  // 7. x1 = x + o @ w_o.T
  gemm_k<float, true, false, false, 2><<<dim3(8, 16, 1), 256, 0, stream>>>(
      o_attn, w_o, nullptr, nullptr, nullptr, x1, x, nullptr,
      T_, H_, H_, H_, H_, H_, 1.f, 0, 1, 0, nullptr, nullptr, nullptr, 0, 0, 0, 1);

  // scoresP dead -> zero g/u accumulators
  hipMemsetAsync(g_f32, 0, (size_t)T_ * TOPK_ * I_ * 8, stream);

  // 8. h2 = rmsnorm(x1, w_rms2)
  rmsnorm_k<<<T_, 256, 0, stream>>>(x1, w_rms2, h2b, h2f);

  // 9. router
  router_k<<<T_ * E_, 64, 0, stream>>>(h2f, w_router, logits);
  topk_k<<<4, 256, 0, stream>>>(logits, topi, topw);
  hist_k<<<16, 256, 0, stream>>>(topi, cnt);
  scan_k<<<1, 64, 0, stream>>>(cnt, eoffp, cursor);
  scatter_k<<<16, 256, 0, stream>>>(topi, topw, cursor, slots, slotw);

  // 10. fused grouped up: g += X_e @ w1[e] (x<8), u += X_e @ w3[e] (x>=8)
  moe_gemm_k<0, true><<<dim3(16, E_ * 8, 2), 512, 0, stream>>>(
      h2b, w1, w3, g_f32, u_f32,
      I_, H_, I_, H_ / 2, eoffp, slots, nullptr, (long long)H_ * I_);
  silumul_f_k<<<(T_ * TOPK_ * I_) / (256 * 8), 256, 0, stream>>>(g_f32, u_f32, a_g);

  // 11. grouped down: routed[t] += w * (a_e @ w2[e])
  moe_gemm_k<1, false><<<dim3(16, E_ * 8, 2), 512, 0, stream>>>(
      a_g, w2, nullptr, routed, nullptr,
      H_, I_, H_, I_ / 2, eoffp, slots, slotw, (long long)I_ * H_);

  // 12. shared expert
  gemm_k<float, true, false, false, 0><<<dim3(8, 16, 1), 256, 0, stream>>>(
      h2b, ws_gu, nullptr, gub, nullptr, nullptr, nullptr, nullptr,
      T_, 2 * I_, H_, H_, H_, 2 * I_, 1.f, 0, 1, 0, nullptr, nullptr, nullptr, 0, 0, 0, 1);
  sharedact_k<<<(T_ * I_) / (256 * 8), 256, 0, stream>>>(gub, actsh);

  // 13. out = f32(x1 + routed + act @ ws_down.T)
  gemm_k<float, true, false, false, 4><<<dim3(8, 16, 1), 256, 0, stream>>>(
      actsh, ws_dn, nullptr, nullptr, nullptr, out, x1, routed,
      T_, H_, I_, I_, I_, H_, 1.f, 0, 1, 0, nullptr, nullptr, nullptr, 0, 0, 0, 1);
}